// Round 1
// baseline (799.116 us; speedup 1.0000x reference)
//
#include <hip/hip_runtime.h>
#include <hip/hip_bf16.h>

#define NNODES 50000
#define NEDGES 800000
#define FDIM   128
#define NHEADS 4
#define HC     32     // channels per head
#define ROWS   32     // rows per block in GEMM

// ---------------------------------------------------------------------------
// K1: fused GEMM  q,k,v = x@W* + b*;  out = x@Wskip + bskip
// 128 threads/block, ROWS rows per block. x rows staged in LDS; 4 matrices
// accumulated together so each LDS read feeds 16 FMAs.
// ---------------------------------------------------------------------------
__global__ __launch_bounds__(128) void tgd_gemm(
    const float* __restrict__ x,
    const float* __restrict__ Wq, const float* __restrict__ bq,
    const float* __restrict__ Wk, const float* __restrict__ bk,
    const float* __restrict__ Wv, const float* __restrict__ bv,
    const float* __restrict__ Wsk, const float* __restrict__ bsk,
    float* __restrict__ q, float* __restrict__ k, float* __restrict__ v,
    float* __restrict__ outp)
{
    __shared__ float xs[ROWS][FDIM];
    const int tid  = threadIdx.x;
    const int row0 = blockIdx.x * ROWS;

    #pragma unroll
    for (int r = 0; r < ROWS; ++r) {
        int row = row0 + r;
        xs[r][tid] = (row < NNODES) ? x[(size_t)row * FDIM + tid] : 0.0f;
    }
    __syncthreads();

    float acc[4][ROWS];
    #pragma unroll
    for (int m = 0; m < 4; ++m)
        #pragma unroll
        for (int r = 0; r < ROWS; ++r) acc[m][r] = 0.0f;

    const float* W[4] = {Wq, Wk, Wv, Wsk};

    for (int i = 0; i < FDIM; i += 4) {
        float4 w4[4];
        #pragma unroll
        for (int m = 0; m < 4; ++m) {
            w4[m].x = W[m][(size_t)(i + 0) * FDIM + tid];
            w4[m].y = W[m][(size_t)(i + 1) * FDIM + tid];
            w4[m].z = W[m][(size_t)(i + 2) * FDIM + tid];
            w4[m].w = W[m][(size_t)(i + 3) * FDIM + tid];
        }
        #pragma unroll
        for (int r = 0; r < ROWS; ++r) {
            float4 x4 = *reinterpret_cast<const float4*>(&xs[r][i]);
            #pragma unroll
            for (int m = 0; m < 4; ++m) {
                acc[m][r] += x4.x * w4[m].x + x4.y * w4[m].y
                           + x4.z * w4[m].z + x4.w * w4[m].w;
            }
        }
    }

    const float* bias[4] = {bq, bk, bv, bsk};
    float* dst[4] = {q, k, v, outp};
    #pragma unroll
    for (int m = 0; m < 4; ++m) {
        float b = bias[m][tid];
        #pragma unroll
        for (int r = 0; r < ROWS; ++r) {
            int row = row0 + r;
            if (row < NNODES) dst[m][(size_t)row * FDIM + tid] = acc[m][r] + b;
        }
    }
}

// ---------------------------------------------------------------------------
// K2: per-edge attention logits -> ex = exp(q[dst]·k[src]/sqrt(C)) per head,
// and atomic accumulation of denom[dst,h]. 32 lanes per edge.
// ---------------------------------------------------------------------------
__global__ __launch_bounds__(256) void tgd_edge_alpha(
    const int* __restrict__ ei,
    const float* __restrict__ q, const float* __restrict__ k,
    float* __restrict__ ex, float* __restrict__ denom)
{
    const int t = blockIdx.x * 256 + threadIdx.x;
    const int e = t >> 5;
    const int c = t & 31;
    if (e >= NEDGES) return;

    const int src = ei[e];
    const int dst = ei[NEDGES + e];

    const float* qr = q + (size_t)dst * FDIM;
    const float* kr = k + (size_t)src * FDIM;

    float s0 = qr[c]      * kr[c];
    float s1 = qr[32 + c] * kr[32 + c];
    float s2 = qr[64 + c] * kr[64 + c];
    float s3 = qr[96 + c] * kr[96 + c];

    #pragma unroll
    for (int m = 16; m >= 1; m >>= 1) {
        s0 += __shfl_xor(s0, m);
        s1 += __shfl_xor(s1, m);
        s2 += __shfl_xor(s2, m);
        s3 += __shfl_xor(s3, m);
    }

    if (c == 0) {
        const float inv = 0.17677669529663687f;  // 1/sqrt(32)
        float e0 = __expf(s0 * inv);
        float e1 = __expf(s1 * inv);
        float e2 = __expf(s2 * inv);
        float e3 = __expf(s3 * inv);
        ex[(size_t)e * 4 + 0] = e0;
        ex[(size_t)e * 4 + 1] = e1;
        ex[(size_t)e * 4 + 2] = e2;
        ex[(size_t)e * 4 + 3] = e3;
        atomicAdd(&denom[(size_t)dst * 4 + 0], e0);
        atomicAdd(&denom[(size_t)dst * 4 + 1], e1);
        atomicAdd(&denom[(size_t)dst * 4 + 2], e2);
        atomicAdd(&denom[(size_t)dst * 4 + 3], e3);
    }
}

// ---------------------------------------------------------------------------
// K2b: normalize edge weights in place: ex[e,h] /= denom[dst,h]
// ---------------------------------------------------------------------------
__global__ __launch_bounds__(256) void tgd_wnorm(
    const int* __restrict__ ei,
    float* __restrict__ ex, const float* __restrict__ denom)
{
    const int t = blockIdx.x * 256 + threadIdx.x;
    if (t >= NEDGES * NHEADS) return;
    const int e = t >> 2;
    const int h = t & 3;
    const int dst = ei[NEDGES + e];
    ex[t] = ex[t] / denom[(size_t)dst * 4 + h];
}

// ---------------------------------------------------------------------------
// K3: weighted scatter-add of v[src] into out[dst]. 128 threads per edge.
// ---------------------------------------------------------------------------
__global__ __launch_bounds__(256) void tgd_scatter(
    const int* __restrict__ ei,
    const float* __restrict__ v, const float* __restrict__ ex,
    float* __restrict__ outp)
{
    const long long t = (long long)blockIdx.x * 256 + threadIdx.x;
    const int e = (int)(t >> 7);
    const int i = (int)(t & 127);
    if (e >= NEDGES) return;

    const int src = ei[e];
    const int dst = ei[NEDGES + e];
    const int h = i >> 5;

    float w   = ex[(size_t)e * 4 + h];
    float val = v[(size_t)src * FDIM + i] * w;
    atomicAdd(&outp[(size_t)dst * FDIM + i], val);
}

// ---------------------------------------------------------------------------
extern "C" void kernel_launch(void* const* d_in, const int* in_sizes, int n_in,
                              void* d_out, int out_size, void* d_ws, size_t ws_size,
                              hipStream_t stream) {
    const float* x   = (const float*)d_in[0];
    const int*   ei  = (const int*)  d_in[1];
    const float* Wq  = (const float*)d_in[2];
    const float* bq  = (const float*)d_in[3];
    const float* Wk  = (const float*)d_in[4];
    const float* bk  = (const float*)d_in[5];
    const float* Wv  = (const float*)d_in[6];
    const float* bv  = (const float*)d_in[7];
    const float* Wsk = (const float*)d_in[8];
    const float* bsk = (const float*)d_in[9];
    float* outp = (float*)d_out;

    float* ws    = (float*)d_ws;
    float* q     = ws;                         // N*128 = 6.4M floats
    float* k     = ws + (size_t)NNODES * FDIM;           // 6.4M
    float* v     = ws + (size_t)2 * NNODES * FDIM;       // 6.4M
    float* ex    = ws + (size_t)3 * NNODES * FDIM;       // E*4 = 3.2M
    float* denom = ex + (size_t)NEDGES * NHEADS;         // N*4 = 0.2M

    // zero-init denom (ws is poisoned 0xAA before every call)
    hipMemsetAsync(denom, 0, (size_t)NNODES * NHEADS * sizeof(float), stream);

    // K1: fused qkv + skip GEMM
    int gemm_blocks = (NNODES + ROWS - 1) / ROWS;
    tgd_gemm<<<gemm_blocks, 128, 0, stream>>>(x, Wq, bq, Wk, bk, Wv, bv, Wsk, bsk,
                                              q, k, v, outp);

    // K2: per-edge exp(logit) + denom accumulation (32 lanes/edge)
    int k2_blocks = (NEDGES * 32) / 256;
    tgd_edge_alpha<<<k2_blocks, 256, 0, stream>>>(ei, q, k, ex, denom);

    // K2b: normalize weights
    int k2b_blocks = (NEDGES * NHEADS + 255) / 256;
    tgd_wnorm<<<k2b_blocks, 256, 0, stream>>>(ei, ex, denom);

    // K3: weighted scatter of v
    long long k3_threads = (long long)NEDGES * FDIM;
    int k3_blocks = (int)(k3_threads / 256);
    tgd_scatter<<<k3_blocks, 256, 0, stream>>>(ei, v, ex, outp);
}

// Round 4
// 572.790 us; speedup vs baseline: 1.3951x; 1.3951x over previous
//
#include <hip/hip_runtime.h>
#include <hip/hip_bf16.h>

#define NNODES 50000
#define NEDGES 800000
#define FDIM   128
#define NHEADS 4
#define HC     32
#define ROWS   32

// ---------------------------------------------------------------------------
// K1: fused GEMM  q,k,v = x@W* + b*;  out = x@Wskip + bskip
// ---------------------------------------------------------------------------
__global__ __launch_bounds__(128) void tgd_gemm(
    const float* __restrict__ x,
    const float* __restrict__ Wq, const float* __restrict__ bq,
    const float* __restrict__ Wk, const float* __restrict__ bk,
    const float* __restrict__ Wv, const float* __restrict__ bv,
    const float* __restrict__ Wsk, const float* __restrict__ bsk,
    float* __restrict__ q, float* __restrict__ k, float* __restrict__ v,
    float* __restrict__ outp)
{
    __shared__ float xs[ROWS][FDIM];
    const int tid  = threadIdx.x;
    const int row0 = blockIdx.x * ROWS;

    #pragma unroll
    for (int r = 0; r < ROWS; ++r) {
        int row = row0 + r;
        xs[r][tid] = (row < NNODES) ? x[(size_t)row * FDIM + tid] : 0.0f;
    }
    __syncthreads();

    float acc[4][ROWS];
    #pragma unroll
    for (int m = 0; m < 4; ++m)
        #pragma unroll
        for (int r = 0; r < ROWS; ++r) acc[m][r] = 0.0f;

    const float* W[4] = {Wq, Wk, Wv, Wsk};

    for (int i = 0; i < FDIM; i += 4) {
        float4 w4[4];
        #pragma unroll
        for (int m = 0; m < 4; ++m) {
            w4[m].x = W[m][(size_t)(i + 0) * FDIM + tid];
            w4[m].y = W[m][(size_t)(i + 1) * FDIM + tid];
            w4[m].z = W[m][(size_t)(i + 2) * FDIM + tid];
            w4[m].w = W[m][(size_t)(i + 3) * FDIM + tid];
        }
        #pragma unroll
        for (int r = 0; r < ROWS; ++r) {
            float4 x4 = *reinterpret_cast<const float4*>(&xs[r][i]);
            #pragma unroll
            for (int m = 0; m < 4; ++m) {
                acc[m][r] += x4.x * w4[m].x + x4.y * w4[m].y
                           + x4.z * w4[m].z + x4.w * w4[m].w;
            }
        }
    }

    const float* bias[4] = {bq, bk, bv, bsk};
    float* dst[4] = {q, k, v, outp};
    #pragma unroll
    for (int m = 0; m < 4; ++m) {
        float b = bias[m][tid];
        #pragma unroll
        for (int r = 0; r < ROWS; ++r) {
            int row = row0 + r;
            if (row < NNODES) dst[m][(size_t)row * FDIM + tid] = acc[m][r] + b;
        }
    }
}

// ---------------------------------------------------------------------------
// CSR build: histogram -> exclusive scan -> scatter src ids
// ---------------------------------------------------------------------------
__global__ __launch_bounds__(256) void tgd_hist(const int* __restrict__ ei,
                                                int* __restrict__ deg)
{
    int t = blockIdx.x * 256 + threadIdx.x;
    if (t < NEDGES) atomicAdd(&deg[ei[NEDGES + t]], 1);
}

__global__ __launch_bounds__(1024) void tgd_scan(const int* __restrict__ deg,
                                                 int* __restrict__ rowptr,
                                                 int* __restrict__ ofs)
{
    __shared__ int buf[1024];
    __shared__ int carry_s;
    const int tid = threadIdx.x;
    if (tid == 0) { carry_s = 0; rowptr[0] = 0; }
    __syncthreads();
    for (int base = 0; base < NNODES; base += 1024) {
        int i = base + tid;
        int d = (i < NNODES) ? deg[i] : 0;
        buf[tid] = d;
        __syncthreads();
        #pragma unroll
        for (int off = 1; off < 1024; off <<= 1) {
            int t2 = (tid >= off) ? buf[tid - off] : 0;
            __syncthreads();
            buf[tid] += t2;
            __syncthreads();
        }
        int c    = carry_s;
        int incl = buf[tid];
        if (i < NNODES) {
            rowptr[i + 1] = c + incl;
            ofs[i]        = c + incl - d;   // exclusive prefix = write cursor
        }
        __syncthreads();
        if (tid == 1023) carry_s = c + incl;
        __syncthreads();
    }
}

__global__ __launch_bounds__(256) void tgd_build(const int* __restrict__ ei,
                                                 int* __restrict__ ofs,
                                                 int* __restrict__ csr)
{
    int t = blockIdx.x * 256 + threadIdx.x;
    if (t >= NEDGES) return;
    int src = ei[t];
    int dst = ei[NEDGES + t];
    int pos = atomicAdd(&ofs[dst], 1);
    csr[pos] = src;
}

// ---------------------------------------------------------------------------
// Fused per-dst aggregation: dot(q,k) -> softmax (no max-shift; |alpha|<~3)
// -> weighted sum of v -> out += agg/den. One 128-thread block per node.
// ---------------------------------------------------------------------------
__global__ __launch_bounds__(128) void tgd_agg(
    const int* __restrict__ csr, const int* __restrict__ rowptr,
    const float* __restrict__ q, const float* __restrict__ k,
    const float* __restrict__ v, float* __restrict__ outp)
{
    const int n   = blockIdx.x;
    const int tid = threadIdx.x;          // channel; head = tid>>5
    const int start = rowptr[n];
    const int end   = rowptr[n + 1];
    if (start == end) return;             // deg-0: out stays = skip

    const float qc  = q[(size_t)n * FDIM + tid];
    const float inv = 0.17677669529663687f;  // 1/sqrt(32)
    float acc = 0.0f, den = 0.0f;

    for (int i = start; i < end; ++i) {
        int src = csr[i];                 // uniform scalar load
        float kv = k[(size_t)src * FDIM + tid];
        float vv = v[(size_t)src * FDIM + tid];
        float s = qc * kv;
        #pragma unroll
        for (int m = 16; m >= 1; m >>= 1)  // xor masks stay in 32-lane head group
            s += __shfl_xor(s, m);
        float w = __expf(s * inv);
        den += w;
        acc += w * vv;
    }
    outp[(size_t)n * FDIM + tid] += acc / den;
}

// ---------------------------------------------------------------------------
extern "C" void kernel_launch(void* const* d_in, const int* in_sizes, int n_in,
                              void* d_out, int out_size, void* d_ws, size_t ws_size,
                              hipStream_t stream) {
    const float* x   = (const float*)d_in[0];
    const int*   ei  = (const int*)  d_in[1];
    const float* Wq  = (const float*)d_in[2];
    const float* bq  = (const float*)d_in[3];
    const float* Wk  = (const float*)d_in[4];
    const float* bk  = (const float*)d_in[5];
    const float* Wv  = (const float*)d_in[6];
    const float* bv  = (const float*)d_in[7];
    const float* Wsk = (const float*)d_in[8];
    const float* bsk = (const float*)d_in[9];
    float* outp = (float*)d_out;

    float* ws = (float*)d_ws;
    float* q  = ws;
    float* k  = ws + (size_t)NNODES * FDIM;
    float* v  = ws + (size_t)2 * NNODES * FDIM;
    int* deg    = (int*)(ws + (size_t)3 * NNODES * FDIM);
    int* rowptr = deg + NNODES;            // N+1
    int* ofs    = rowptr + NNODES + 1;     // N
    int* csr    = ofs + NNODES;            // E

    hipMemsetAsync(deg, 0, (size_t)NNODES * sizeof(int), stream);

    int gemm_blocks = (NNODES + ROWS - 1) / ROWS;
    tgd_gemm<<<gemm_blocks, 128, 0, stream>>>(x, Wq, bq, Wk, bk, Wv, bv, Wsk, bsk,
                                              q, k, v, outp);

    tgd_hist<<<(NEDGES + 255) / 256, 256, 0, stream>>>(ei, deg);
    tgd_scan<<<1, 1024, 0, stream>>>(deg, rowptr, ofs);
    tgd_build<<<(NEDGES + 255) / 256, 256, 0, stream>>>(ei, ofs, csr);
    tgd_agg<<<NNODES, 128, 0, stream>>>(csr, rowptr, q, k, v, outp);
}

// Round 5
// 480.051 us; speedup vs baseline: 1.6646x; 1.1932x over previous
//
#include <hip/hip_runtime.h>
#include <hip/hip_bf16.h>

#define NNODES 50000
#define NEDGES 800000
#define FDIM   128
#define NHEADS 4

typedef __attribute__((ext_vector_type(8))) short  bf16x8;
typedef __attribute__((ext_vector_type(4))) float  f32x4;

static __device__ __forceinline__ unsigned short f2bf(float f) {
    __hip_bfloat16 h = __float2bfloat16(f);
    return *reinterpret_cast<unsigned short*>(&h);
}

// ---------------------------------------------------------------------------
// Convert x (fp32 row-major) -> bf16 row-major. 8 elems/thread.
// ---------------------------------------------------------------------------
__global__ __launch_bounds__(256) void tgd_cvt_x(const float* __restrict__ x,
                                                 unsigned short* __restrict__ xb)
{
    size_t base = ((size_t)blockIdx.x * 256 + threadIdx.x) * 8;
    if (base >= (size_t)NNODES * FDIM) return;
    float4 f0 = *reinterpret_cast<const float4*>(&x[base]);
    float4 f1 = *reinterpret_cast<const float4*>(&x[base + 4]);
    unsigned short u[8];
    u[0]=f2bf(f0.x); u[1]=f2bf(f0.y); u[2]=f2bf(f0.z); u[3]=f2bf(f0.w);
    u[4]=f2bf(f1.x); u[5]=f2bf(f1.y); u[6]=f2bf(f1.z); u[7]=f2bf(f1.w);
    *reinterpret_cast<uint4*>(&xb[base]) = *reinterpret_cast<uint4*>(u);
}

// ---------------------------------------------------------------------------
// Transpose+convert weights: Wt[m][c][k] = W_m[k][c] as bf16.
// grid = 4*128 blocks (one per (m,c)), 128 threads (k).
// ---------------------------------------------------------------------------
__global__ __launch_bounds__(128) void tgd_cvt_w(
    const float* __restrict__ Wq, const float* __restrict__ Wk,
    const float* __restrict__ Wv, const float* __restrict__ Wsk,
    unsigned short* __restrict__ Wt)
{
    int m = blockIdx.x >> 7;
    int c = blockIdx.x & 127;
    int k = threadIdx.x;
    const float* W = (m == 0) ? Wq : (m == 1) ? Wk : (m == 2) ? Wv : Wsk;
    Wt[((size_t)(m * FDIM + c)) * FDIM + k] = f2bf(W[(size_t)k * FDIM + c]);
}

// ---------------------------------------------------------------------------
// MFMA GEMM: computes all 4 projections.
//   q   (fp32 [N,128]), skip -> outp (fp32 [N,128]),
//   k,v -> kv (bf16 [N,256]: cols 0..127 = k, 128..255 = v)
// Block = 512 threads (8 waves), 64 rows/block.
// wave: mp = wave>>2 selects matrix pair {q,k} / {v,skip}; wr = wave&3 row group.
// Fragment layout (m92/m97-verified): A row = lane&15, k = (lane>>4)*8+j;
// B col = lane&15, same k; C col = lane&15, row = (lane>>4)*4+reg.
// ---------------------------------------------------------------------------
__global__ __launch_bounds__(512) void tgd_gemm_mfma(
    const unsigned short* __restrict__ xb, const unsigned short* __restrict__ Wt,
    const float* __restrict__ bq, const float* __restrict__ bk,
    const float* __restrict__ bv, const float* __restrict__ bsk,
    float* __restrict__ q, unsigned short* __restrict__ kv,
    float* __restrict__ outp)
{
    const int tid  = threadIdx.x;
    const int wave = tid >> 6, lane = tid & 63;
    const int mp   = wave >> 2;           // 0: (q,k)  1: (v,skip)
    const int wr   = wave & 3;
    const int r0   = blockIdx.x * 64 + wr * 16;
    const int l16  = lane & 15, lhi = lane >> 4;

    // A fragments for all 4 k-slices (lane holds row r0+l16, k = ks*32+lhi*8..+7)
    int arow = r0 + l16;
    int arow_c = (arow < NNODES) ? arow : (NNODES - 1);
    const unsigned short* abase = xb + (size_t)arow_c * FDIM + lhi * 8;
    bf16x8 a[4];
    #pragma unroll
    for (int ks = 0; ks < 4; ++ks)
        a[ks] = *reinterpret_cast<const bf16x8*>(abase + ks * 32);

    f32x4 acc[2][8];
    #pragma unroll
    for (int m2 = 0; m2 < 2; ++m2)
        #pragma unroll
        for (int ct = 0; ct < 8; ++ct)
            acc[m2][ct] = (f32x4){0.f, 0.f, 0.f, 0.f};

    #pragma unroll
    for (int ks = 0; ks < 4; ++ks) {
        #pragma unroll
        for (int m2 = 0; m2 < 2; ++m2) {
            const unsigned short* wb =
                Wt + (size_t)((mp * 2 + m2) * FDIM) * FDIM + ks * 32 + lhi * 8;
            #pragma unroll
            for (int ct = 0; ct < 8; ++ct) {
                bf16x8 b = *reinterpret_cast<const bf16x8*>(
                    wb + (size_t)(ct * 16 + l16) * FDIM);
                acc[m2][ct] = __builtin_amdgcn_mfma_f32_16x16x32_bf16(
                    a[ks], b, acc[m2][ct], 0, 0, 0);
            }
        }
    }

    // Epilogue: bias + route to destination
    #pragma unroll
    for (int m2 = 0; m2 < 2; ++m2) {
        const int m = mp * 2 + m2;
        const float* bias = (m == 0) ? bq : (m == 1) ? bk : (m == 2) ? bv : bsk;
        #pragma unroll
        for (int ct = 0; ct < 8; ++ct) {
            int col = ct * 16 + l16;
            float bval = bias[col];
            #pragma unroll
            for (int r = 0; r < 4; ++r) {
                int row = r0 + lhi * 4 + r;
                if (row >= NNODES) continue;
                float val = acc[m2][ct][r] + bval;
                if (m == 0)       q[(size_t)row * FDIM + col] = val;
                else if (m == 3)  outp[(size_t)row * FDIM + col] = val;
                else              kv[(size_t)row * 256 + (m == 2 ? 128 : 0) + col] = f2bf(val);
            }
        }
    }
}

// ---------------------------------------------------------------------------
// CSR build: histogram -> exclusive scan -> scatter src ids
// ---------------------------------------------------------------------------
__global__ __launch_bounds__(256) void tgd_hist(const int* __restrict__ ei,
                                                int* __restrict__ deg)
{
    int t = blockIdx.x * 256 + threadIdx.x;
    if (t < NEDGES) atomicAdd(&deg[ei[NEDGES + t]], 1);
}

__global__ __launch_bounds__(1024) void tgd_scan(const int* __restrict__ deg,
                                                 int* __restrict__ rowptr,
                                                 int* __restrict__ ofs)
{
    __shared__ int buf[1024];
    __shared__ int carry_s;
    const int tid = threadIdx.x;
    if (tid == 0) { carry_s = 0; rowptr[0] = 0; }
    __syncthreads();
    for (int base = 0; base < NNODES; base += 1024) {
        int i = base + tid;
        int d = (i < NNODES) ? deg[i] : 0;
        buf[tid] = d;
        __syncthreads();
        #pragma unroll
        for (int off = 1; off < 1024; off <<= 1) {
            int t2 = (tid >= off) ? buf[tid - off] : 0;
            __syncthreads();
            buf[tid] += t2;
            __syncthreads();
        }
        int c    = carry_s;
        int incl = buf[tid];
        if (i < NNODES) {
            rowptr[i + 1] = c + incl;
            ofs[i]        = c + incl - d;
        }
        __syncthreads();
        if (tid == 1023) carry_s = c + incl;
        __syncthreads();
    }
}

__global__ __launch_bounds__(256) void tgd_build(const int* __restrict__ ei,
                                                 int* __restrict__ ofs,
                                                 int* __restrict__ csr)
{
    int t = blockIdx.x * 256 + threadIdx.x;
    if (t >= NEDGES) return;
    int src = ei[t];
    int dst = ei[NEDGES + t];
    int pos = atomicAdd(&ofs[dst], 1);
    csr[pos] = src;
}

// ---------------------------------------------------------------------------
// Fused per-dst aggregation over CSR. kv is bf16 [node][256] (k | v).
// ---------------------------------------------------------------------------
__global__ __launch_bounds__(128) void tgd_agg(
    const int* __restrict__ csr, const int* __restrict__ rowptr,
    const float* __restrict__ q, const __hip_bfloat16* __restrict__ kv,
    float* __restrict__ outp)
{
    const int n   = blockIdx.x;
    const int tid = threadIdx.x;          // channel; head = tid>>5
    const int start = rowptr[n];
    const int end   = rowptr[n + 1];
    if (start == end) return;             // deg-0: out stays = skip

    const float qc  = q[(size_t)n * FDIM + tid];
    const float inv = 0.17677669529663687f;  // 1/sqrt(32)
    float acc = 0.0f, den = 0.0f;

    for (int i = start; i < end; ++i) {
        int src = csr[i];
        const __hip_bfloat16* row = kv + (size_t)src * 256;
        float kf = __bfloat162float(row[tid]);
        float vf = __bfloat162float(row[128 + tid]);
        float s = qc * kf;
        #pragma unroll
        for (int m = 16; m >= 1; m >>= 1)
            s += __shfl_xor(s, m);
        float w = __expf(s * inv);
        den += w;
        acc += w * vf;
    }
    outp[(size_t)n * FDIM + tid] += acc / den;
}

// ---------------------------------------------------------------------------
extern "C" void kernel_launch(void* const* d_in, const int* in_sizes, int n_in,
                              void* d_out, int out_size, void* d_ws, size_t ws_size,
                              hipStream_t stream) {
    const float* x   = (const float*)d_in[0];
    const int*   ei  = (const int*)  d_in[1];
    const float* Wq  = (const float*)d_in[2];
    const float* bq  = (const float*)d_in[3];
    const float* Wk  = (const float*)d_in[4];
    const float* bk  = (const float*)d_in[5];
    const float* Wv  = (const float*)d_in[6];
    const float* bv  = (const float*)d_in[7];
    const float* Wsk = (const float*)d_in[8];
    const float* bsk = (const float*)d_in[9];
    float* outp = (float*)d_out;

    // workspace layout
    float* ws = (float*)d_ws;
    float*          q   = ws;                                   // 6.4M f32  (25.6MB)
    unsigned short* kv  = (unsigned short*)(q + (size_t)NNODES * FDIM);  // N*256 bf16 (25.6MB)
    unsigned short* xb  = kv + (size_t)NNODES * 256;            // N*128 bf16 (12.8MB)
    unsigned short* Wt  = xb + (size_t)NNODES * FDIM;           // 4*128*128 bf16 (128KB)
    int* deg    = (int*)(Wt + 4 * FDIM * FDIM);                 // N
    int* rowptr = deg + NNODES;                                 // N+1
    int* ofs    = rowptr + NNODES + 1;                          // N
    int* csr    = ofs + NNODES;                                 // E

    hipMemsetAsync(deg, 0, (size_t)NNODES * sizeof(int), stream);

    // conversions
    tgd_cvt_x<<<(NNODES * FDIM / 8 + 255) / 256, 256, 0, stream>>>(x, xb);
    tgd_cvt_w<<<4 * FDIM, 128, 0, stream>>>(Wq, Wk, Wv, Wsk, Wt);

    // fused 4-way MFMA GEMM
    tgd_gemm_mfma<<<(NNODES + 63) / 64, 512, 0, stream>>>(
        xb, Wt, bq, bk, bv, bsk, q, kv, outp);

    // CSR build + aggregation
    tgd_hist<<<(NEDGES + 255) / 256, 256, 0, stream>>>(ei, deg);
    tgd_scan<<<1, 1024, 0, stream>>>(deg, rowptr, ofs);
    tgd_build<<<(NEDGES + 255) / 256, 256, 0, stream>>>(ei, ofs, csr);
    tgd_agg<<<NNODES, 128, 0, stream>>>(csr, rowptr, q, (const __hip_bfloat16*)kv, outp);
}

// Round 10
// 341.040 us; speedup vs baseline: 2.3432x; 1.4076x over previous
//
#include <hip/hip_runtime.h>
#include <hip/hip_bf16.h>

#define NNODES 50000
#define NEDGES 800000
#define FDIM   128
#define NHEADS 4
#define NSCANB ((NNODES + 1023) / 1024)   // 49

typedef __attribute__((ext_vector_type(8))) short  bf16x8;
typedef __attribute__((ext_vector_type(4))) float  f32x4;

static __device__ __forceinline__ unsigned short f2bf(float f) {
    __hip_bfloat16 h = __float2bfloat16(f);
    return *reinterpret_cast<unsigned short*>(&h);
}
static __device__ __forceinline__ float bf2f(unsigned short u) {
    return __uint_as_float(((unsigned int)u) << 16);
}

// ---------------------------------------------------------------------------
// Convert x (fp32) -> bf16. 8 elems/thread.
// ---------------------------------------------------------------------------
__global__ __launch_bounds__(256) void tgd_cvt_x(const float* __restrict__ x,
                                                 unsigned short* __restrict__ xb)
{
    size_t base = ((size_t)blockIdx.x * 256 + threadIdx.x) * 8;
    if (base >= (size_t)NNODES * FDIM) return;
    float4 f0 = *reinterpret_cast<const float4*>(&x[base]);
    float4 f1 = *reinterpret_cast<const float4*>(&x[base + 4]);
    unsigned short u[8];
    u[0]=f2bf(f0.x); u[1]=f2bf(f0.y); u[2]=f2bf(f0.z); u[3]=f2bf(f0.w);
    u[4]=f2bf(f1.x); u[5]=f2bf(f1.y); u[6]=f2bf(f1.z); u[7]=f2bf(f1.w);
    *reinterpret_cast<uint4*>(&xb[base]) = *reinterpret_cast<uint4*>(u);
}

// ---------------------------------------------------------------------------
// Transpose+convert weights: Wt[m][c][k] = W_m[k][c] as bf16.
// ---------------------------------------------------------------------------
__global__ __launch_bounds__(128) void tgd_cvt_w(
    const float* __restrict__ Wq, const float* __restrict__ Wk,
    const float* __restrict__ Wv, const float* __restrict__ Wsk,
    unsigned short* __restrict__ Wt)
{
    int m = blockIdx.x >> 7;
    int c = blockIdx.x & 127;
    int k = threadIdx.x;
    const float* W = (m == 0) ? Wq : (m == 1) ? Wk : (m == 2) ? Wv : Wsk;
    Wt[((size_t)(m * FDIM + c)) * FDIM + k] = f2bf(W[(size_t)k * FDIM + c]);
}

// ---------------------------------------------------------------------------
// MFMA GEMM: q (fp32), skip->outp (fp32), k,v -> kv bf16 [N][256] (k | v).
// 512 threads (8 waves), 64 rows/block. (layout per m92/m97, verified r5)
// ---------------------------------------------------------------------------
__global__ __launch_bounds__(512) void tgd_gemm_mfma(
    const unsigned short* __restrict__ xb, const unsigned short* __restrict__ Wt,
    const float* __restrict__ bq, const float* __restrict__ bk,
    const float* __restrict__ bv, const float* __restrict__ bsk,
    float* __restrict__ q, unsigned short* __restrict__ kv,
    float* __restrict__ outp)
{
    const int tid  = threadIdx.x;
    const int wave = tid >> 6, lane = tid & 63;
    const int mp   = wave >> 2;           // 0: (q,k)  1: (v,skip)
    const int wr   = wave & 3;
    const int r0   = blockIdx.x * 64 + wr * 16;
    const int l16  = lane & 15, lhi = lane >> 4;

    int arow = r0 + l16;
    int arow_c = (arow < NNODES) ? arow : (NNODES - 1);
    const unsigned short* abase = xb + (size_t)arow_c * FDIM + lhi * 8;
    bf16x8 a[4];
    #pragma unroll
    for (int ks = 0; ks < 4; ++ks)
        a[ks] = *reinterpret_cast<const bf16x8*>(abase + ks * 32);

    f32x4 acc[2][8];
    #pragma unroll
    for (int m2 = 0; m2 < 2; ++m2)
        #pragma unroll
        for (int ct = 0; ct < 8; ++ct)
            acc[m2][ct] = (f32x4){0.f, 0.f, 0.f, 0.f};

    #pragma unroll
    for (int ks = 0; ks < 4; ++ks) {
        #pragma unroll
        for (int m2 = 0; m2 < 2; ++m2) {
            const unsigned short* wb =
                Wt + (size_t)((mp * 2 + m2) * FDIM) * FDIM + ks * 32 + lhi * 8;
            #pragma unroll
            for (int ct = 0; ct < 8; ++ct) {
                bf16x8 b = *reinterpret_cast<const bf16x8*>(
                    wb + (size_t)(ct * 16 + l16) * FDIM);
                acc[m2][ct] = __builtin_amdgcn_mfma_f32_16x16x32_bf16(
                    a[ks], b, acc[m2][ct], 0, 0, 0);
            }
        }
    }

    #pragma unroll
    for (int m2 = 0; m2 < 2; ++m2) {
        const int m = mp * 2 + m2;
        const float* bias = (m == 0) ? bq : (m == 1) ? bk : (m == 2) ? bv : bsk;
        #pragma unroll
        for (int ct = 0; ct < 8; ++ct) {
            int col = ct * 16 + l16;
            float bval = bias[col];
            #pragma unroll
            for (int r = 0; r < 4; ++r) {
                int row = r0 + lhi * 4 + r;
                if (row >= NNODES) continue;
                float val = acc[m2][ct][r] + bval;
                if (m == 0)       q[(size_t)row * FDIM + col] = val;
                else if (m == 3)  outp[(size_t)row * FDIM + col] = val;
                else              kv[(size_t)row * 256 + (m == 2 ? 128 : 0) + col] = f2bf(val);
            }
        }
    }
}

// ---------------------------------------------------------------------------
// CSR build: histogram -> hierarchical scan -> scatter src ids
// ---------------------------------------------------------------------------
__global__ __launch_bounds__(256) void tgd_hist(const int* __restrict__ ei,
                                                int* __restrict__ deg)
{
    int t = blockIdx.x * 256 + threadIdx.x;
    if (t < NEDGES) atomicAdd(&deg[ei[NEDGES + t]], 1);
}

// local inclusive scan per 1024-block; block total -> bsum
__global__ __launch_bounds__(1024) void tgd_scan1(const int* __restrict__ deg,
                                                  int* __restrict__ rowptr,
                                                  int* __restrict__ bsum)
{
    __shared__ int buf[1024];
    const int tid = threadIdx.x;
    const int i   = blockIdx.x * 1024 + tid;
    int d = (i < NNODES) ? deg[i] : 0;
    buf[tid] = d;
    __syncthreads();
    #pragma unroll
    for (int off = 1; off < 1024; off <<= 1) {
        int t2 = (tid >= off) ? buf[tid - off] : 0;
        __syncthreads();
        buf[tid] += t2;
        __syncthreads();
    }
    if (i < NNODES) rowptr[i + 1] = buf[tid];   // local inclusive (pre-offset)
    if (tid == 1023) bsum[blockIdx.x] = buf[1023];
}

// one wave scans the 49 block sums -> exclusive offsets
__global__ __launch_bounds__(64) void tgd_scan2(const int* __restrict__ bsum,
                                                int* __restrict__ boff)
{
    int lane = threadIdx.x;
    int v = (lane < NSCANB) ? bsum[lane] : 0;
    int own = v;
    #pragma unroll
    for (int off = 1; off < 64; off <<= 1) {
        int t = __shfl_up(v, off);
        if (lane >= off) v += t;
    }
    if (lane < NSCANB) boff[lane] = v - own;
}

// add block offsets; produce ofs (exclusive) cursors
__global__ __launch_bounds__(1024) void tgd_scan3(const int* __restrict__ deg,
                                                  const int* __restrict__ boff,
                                                  int* __restrict__ rowptr,
                                                  int* __restrict__ ofs)
{
    const int i = blockIdx.x * 1024 + threadIdx.x;
    if (i < NNODES) {
        int r = rowptr[i + 1] + boff[blockIdx.x];
        rowptr[i + 1] = r;
        ofs[i] = r - deg[i];
    }
    if (i == 0) rowptr[0] = 0;
}

__global__ __launch_bounds__(256) void tgd_build(const int* __restrict__ ei,
                                                 int* __restrict__ ofs,
                                                 int* __restrict__ csr)
{
    int t = blockIdx.x * 256 + threadIdx.x;
    if (t >= NEDGES) return;
    int src = ei[t];
    int dst = ei[NEDGES + t];
    int pos = atomicAdd(&ofs[dst], 1);
    csr[pos] = src;
}

// ---------------------------------------------------------------------------
// Fused per-dst aggregation: 1 wave per node. Lane l loads ushort4 at
// kv[src*256 + 4l]: lanes 0..31 hold k (4 ch each), 32..63 hold v.
// Head dot = 3 shfl_xor (8-lane groups); shfl_xor(32) ships w to v-lanes.
// ---------------------------------------------------------------------------
__global__ __launch_bounds__(256) void tgd_agg(
    const int* __restrict__ csr, const int* __restrict__ rowptr,
    const float* __restrict__ q, const unsigned short* __restrict__ kv,
    float* __restrict__ outp)
{
    const int node = blockIdx.x * 4 + (threadIdx.x >> 6);
    const int lane = threadIdx.x & 63;
    if (node >= NNODES) return;
    const int start = rowptr[node];
    const int end   = rowptr[node + 1];
    if (start == end) return;             // deg-0: out stays = skip

    const bool isK = (lane < 32);
    float4 qv = {0.f, 0.f, 0.f, 0.f};
    if (isK) qv = *reinterpret_cast<const float4*>(&q[(size_t)node * FDIM + lane * 4]);
    const float inv = 0.17677669529663687f;  // 1/sqrt(32)

    float  den = 0.0f;
    float4 acc = {0.f, 0.f, 0.f, 0.f};

    for (int base = start; base < end; base += 64) {
        const int cnt = min(64, end - base);
        int myid = (lane < cnt) ? csr[base + lane] : 0;

        int j = 0;
        for (; j + 1 < cnt; j += 2) {
            int s0 = __shfl(myid, j);
            int s1 = __shfl(myid, j + 1);
            ushort4 r0 = *reinterpret_cast<const ushort4*>(&kv[(size_t)s0 * 256 + lane * 4]);
            ushort4 r1 = *reinterpret_cast<const ushort4*>(&kv[(size_t)s1 * 256 + lane * 4]);

            float a0 = bf2f(r0.x), a1 = bf2f(r0.y), a2 = bf2f(r0.z), a3 = bf2f(r0.w);
            float b0 = bf2f(r1.x), b1 = bf2f(r1.y), b2 = bf2f(r1.z), b3 = bf2f(r1.w);

            float sA = qv.x*a0 + qv.y*a1 + qv.z*a2 + qv.w*a3;
            float sB = qv.x*b0 + qv.y*b1 + qv.z*b2 + qv.w*b3;
            sA += __shfl_xor(sA, 1);  sB += __shfl_xor(sB, 1);
            sA += __shfl_xor(sA, 2);  sB += __shfl_xor(sB, 2);
            sA += __shfl_xor(sA, 4);  sB += __shfl_xor(sB, 4);
            float wA = __expf(sA * inv);
            float wB = __expf(sB * inv);
            wA = __shfl_xor(wA, 32);
            wB = __shfl_xor(wB, 32);
            if (!isK) {
                den += wA + wB;
                acc.x += wA*a0 + wB*b0;
                acc.y += wA*a1 + wB*b1;
                acc.z += wA*a2 + wB*b2;
                acc.w += wA*a3 + wB*b3;
            }
        }
        if (j < cnt) {
            int s0 = __shfl(myid, j);
            ushort4 r0 = *reinterpret_cast<const ushort4*>(&kv[(size_t)s0 * 256 + lane * 4]);
            float a0 = bf2f(r0.x), a1 = bf2f(r0.y), a2 = bf2f(r0.z), a3 = bf2f(r0.w);
            float sA = qv.x*a0 + qv.y*a1 + qv.z*a2 + qv.w*a3;
            sA += __shfl_xor(sA, 1);
            sA += __shfl_xor(sA, 2);
            sA += __shfl_xor(sA, 4);
            float wA = __expf(sA * inv);
            wA = __shfl_xor(wA, 32);
            if (!isK) {
                den += wA;
                acc.x += wA*a0; acc.y += wA*a1; acc.z += wA*a2; acc.w += wA*a3;
            }
        }
    }

    if (!isK) {
        float invd = 1.0f / den;
        float4* o = reinterpret_cast<float4*>(&outp[(size_t)node * FDIM + (lane - 32) * 4]);
        float4 cur = *o;
        cur.x += acc.x * invd;
        cur.y += acc.y * invd;
        cur.z += acc.z * invd;
        cur.w += acc.w * invd;
        *o = cur;
    }
}

// ---------------------------------------------------------------------------
extern "C" void kernel_launch(void* const* d_in, const int* in_sizes, int n_in,
                              void* d_out, int out_size, void* d_ws, size_t ws_size,
                              hipStream_t stream) {
    const float* x   = (const float*)d_in[0];
    const int*   ei  = (const int*)  d_in[1];
    const float* Wq  = (const float*)d_in[2];
    const float* bq  = (const float*)d_in[3];
    const float* Wk  = (const float*)d_in[4];
    const float* bk  = (const float*)d_in[5];
    const float* Wv  = (const float*)d_in[6];
    const float* bv  = (const float*)d_in[7];
    const float* Wsk = (const float*)d_in[8];
    const float* bsk = (const float*)d_in[9];
    float* outp = (float*)d_out;

    float* ws = (float*)d_ws;
    float*          q   = ws;                                           // 25.6MB
    unsigned short* kv  = (unsigned short*)(q + (size_t)NNODES * FDIM); // 25.6MB
    unsigned short* xb  = kv + (size_t)NNODES * 256;                    // 12.8MB
    unsigned short* Wt  = xb + (size_t)NNODES * FDIM;                   // 128KB
    int* deg    = (int*)(Wt + 4 * FDIM * FDIM);
    int* rowptr = deg + NNODES;            // N+1
    int* ofs    = rowptr + NNODES + 1;     // N
    int* csr    = ofs + NNODES;            // E
    int* bsum   = csr + NEDGES;            // 49
    int* boff   = bsum + NSCANB;           // 49

    hipMemsetAsync(deg, 0, (size_t)NNODES * sizeof(int), stream);

    tgd_cvt_x<<<(NNODES * FDIM / 8 + 255) / 256, 256, 0, stream>>>(x, xb);
    tgd_cvt_w<<<4 * FDIM, 128, 0, stream>>>(Wq, Wk, Wv, Wsk, Wt);

    tgd_gemm_mfma<<<(NNODES + 63) / 64, 512, 0, stream>>>(
        xb, Wt, bq, bk, bv, bsk, q, kv, outp);

    tgd_hist<<<(NEDGES + 255) / 256, 256, 0, stream>>>(ei, deg);
    tgd_scan1<<<NSCANB, 1024, 0, stream>>>(deg, rowptr, bsum);
    tgd_scan2<<<1, 64, 0, stream>>>(bsum, boff);
    tgd_scan3<<<NSCANB, 1024, 0, stream>>>(deg, boff, rowptr, ofs);
    tgd_build<<<(NEDGES + 255) / 256, 256, 0, stream>>>(ei, ofs, csr);
    tgd_agg<<<(NNODES + 3) / 4, 256, 0, stream>>>(csr, rowptr, q, kv, outp);
}

// Round 11
// 334.229 us; speedup vs baseline: 2.3909x; 1.0204x over previous
//
#include <hip/hip_runtime.h>
#include <hip/hip_bf16.h>

#define NNODES 50000
#define NEDGES 800000
#define FDIM   128
#define NHEADS 4
#define NSCANB ((NNODES + 1023) / 1024)   // 49

typedef __attribute__((ext_vector_type(8))) short  bf16x8;
typedef __attribute__((ext_vector_type(4))) float  f32x4;

static __device__ __forceinline__ unsigned short f2bf(float f) {
    __hip_bfloat16 h = __float2bfloat16(f);
    return *reinterpret_cast<unsigned short*>(&h);
}
static __device__ __forceinline__ float bf2f(unsigned short u) {
    return __uint_as_float(((unsigned int)u) << 16);
}

// ---------------------------------------------------------------------------
// Convert x (fp32) -> bf16. 8 elems/thread.
// ---------------------------------------------------------------------------
__global__ __launch_bounds__(256) void tgd_cvt_x(const float* __restrict__ x,
                                                 unsigned short* __restrict__ xb)
{
    size_t base = ((size_t)blockIdx.x * 256 + threadIdx.x) * 8;
    if (base >= (size_t)NNODES * FDIM) return;
    float4 f0 = *reinterpret_cast<const float4*>(&x[base]);
    float4 f1 = *reinterpret_cast<const float4*>(&x[base + 4]);
    unsigned short u[8];
    u[0]=f2bf(f0.x); u[1]=f2bf(f0.y); u[2]=f2bf(f0.z); u[3]=f2bf(f0.w);
    u[4]=f2bf(f1.x); u[5]=f2bf(f1.y); u[6]=f2bf(f1.z); u[7]=f2bf(f1.w);
    *reinterpret_cast<uint4*>(&xb[base]) = *reinterpret_cast<uint4*>(u);
}

// ---------------------------------------------------------------------------
// Weights -> fragment-ordered bf16 layout:
//   Wt2[(((m*8+ct)*4+ks)*64 + lane)*8 + j] = W_m[k][c]
//   with c = ct*16 + (lane&15), k = ks*32 + (lane>>4)*8 + j.
// A wave's B-fragment load for (m,ct,ks) is then base + lane*16B: one
// contiguous, coalesced 1KB block (single transaction vs 16 before).
// 8192 threads total, 8 elems each.
// ---------------------------------------------------------------------------
__global__ __launch_bounds__(256) void tgd_cvt_w(
    const float* __restrict__ Wq, const float* __restrict__ Wk,
    const float* __restrict__ Wv, const float* __restrict__ Wsk,
    unsigned short* __restrict__ Wt2)
{
    int t = blockIdx.x * 256 + threadIdx.x;   // 0..8191
    if (t >= 4 * 8 * 4 * 64) return;
    int m    = t >> 11;
    int ct   = (t >> 8) & 7;
    int ks   = (t >> 6) & 3;
    int lane = t & 63;
    int c  = ct * 16 + (lane & 15);
    int k0 = ks * 32 + (lane >> 4) * 8;
    const float* W = (m == 0) ? Wq : (m == 1) ? Wk : (m == 2) ? Wv : Wsk;
    unsigned short u[8];
    #pragma unroll
    for (int j = 0; j < 8; ++j)
        u[j] = f2bf(W[(size_t)(k0 + j) * FDIM + c]);
    *reinterpret_cast<uint4*>(&Wt2[(size_t)t * 8]) = *reinterpret_cast<uint4*>(u);
}

// ---------------------------------------------------------------------------
// MFMA GEMM: q (fp32), skip->outp (fp32), k,v -> kv bf16 [N][256] (k | v).
// 512 threads (8 waves), 64 rows/block. B from fragment-ordered Wt2.
// ---------------------------------------------------------------------------
__global__ __launch_bounds__(512) void tgd_gemm_mfma(
    const unsigned short* __restrict__ xb, const unsigned short* __restrict__ Wt2,
    const float* __restrict__ bq, const float* __restrict__ bk,
    const float* __restrict__ bv, const float* __restrict__ bsk,
    float* __restrict__ q, unsigned short* __restrict__ kv,
    float* __restrict__ outp)
{
    const int tid  = threadIdx.x;
    const int wave = tid >> 6, lane = tid & 63;
    const int mp   = wave >> 2;           // 0: (q,k)  1: (v,skip)
    const int wr   = wave & 3;
    const int r0   = blockIdx.x * 64 + wr * 16;
    const int l16  = lane & 15, lhi = lane >> 4;

    int arow = r0 + l16;
    int arow_c = (arow < NNODES) ? arow : (NNODES - 1);
    const unsigned short* abase = xb + (size_t)arow_c * FDIM + lhi * 8;
    bf16x8 a[4];
    #pragma unroll
    for (int ks = 0; ks < 4; ++ks)
        a[ks] = *reinterpret_cast<const bf16x8*>(abase + ks * 32);

    f32x4 acc[2][8];
    #pragma unroll
    for (int m2 = 0; m2 < 2; ++m2)
        #pragma unroll
        for (int ct = 0; ct < 8; ++ct)
            acc[m2][ct] = (f32x4){0.f, 0.f, 0.f, 0.f};

    #pragma unroll
    for (int ks = 0; ks < 4; ++ks) {
        #pragma unroll
        for (int m2 = 0; m2 < 2; ++m2) {
            const int m = mp * 2 + m2;
            const unsigned short* wb =
                Wt2 + ((size_t)(((m * 8 + 0) * 4 + ks) * 64) + lane) * 8;
            #pragma unroll
            for (int ct = 0; ct < 8; ++ct) {
                bf16x8 b = *reinterpret_cast<const bf16x8*>(wb + (size_t)ct * 4 * 64 * 8);
                acc[m2][ct] = __builtin_amdgcn_mfma_f32_16x16x32_bf16(
                    a[ks], b, acc[m2][ct], 0, 0, 0);
            }
        }
    }

    #pragma unroll
    for (int m2 = 0; m2 < 2; ++m2) {
        const int m = mp * 2 + m2;
        const float* bias = (m == 0) ? bq : (m == 1) ? bk : (m == 2) ? bv : bsk;
        #pragma unroll
        for (int ct = 0; ct < 8; ++ct) {
            int col = ct * 16 + l16;
            float bval = bias[col];
            #pragma unroll
            for (int r = 0; r < 4; ++r) {
                int row = r0 + lhi * 4 + r;
                if (row >= NNODES) continue;
                float val = acc[m2][ct][r] + bval;
                if (m == 0)       q[(size_t)row * FDIM + col] = val;
                else if (m == 3)  outp[(size_t)row * FDIM + col] = val;
                else              kv[(size_t)row * 256 + (m == 2 ? 128 : 0) + col] = f2bf(val);
            }
        }
    }
}

// ---------------------------------------------------------------------------
// CSR build: histogram -> hierarchical scan -> scatter src ids
// ---------------------------------------------------------------------------
__global__ __launch_bounds__(256) void tgd_hist(const int* __restrict__ ei,
                                                int* __restrict__ deg)
{
    int t = blockIdx.x * 256 + threadIdx.x;
    if (t < NEDGES) atomicAdd(&deg[ei[NEDGES + t]], 1);
}

// local inclusive scan per 1024-block; block total -> bsum
__global__ __launch_bounds__(1024) void tgd_scan1(const int* __restrict__ deg,
                                                  int* __restrict__ rowptr,
                                                  int* __restrict__ bsum)
{
    __shared__ int buf[1024];
    const int tid = threadIdx.x;
    const int i   = blockIdx.x * 1024 + tid;
    int d = (i < NNODES) ? deg[i] : 0;
    buf[tid] = d;
    __syncthreads();
    #pragma unroll
    for (int off = 1; off < 1024; off <<= 1) {
        int t2 = (tid >= off) ? buf[tid - off] : 0;
        __syncthreads();
        buf[tid] += t2;
        __syncthreads();
    }
    if (i < NNODES) rowptr[i + 1] = buf[tid];   // local inclusive (pre-offset)
    if (tid == 1023) bsum[blockIdx.x] = buf[1023];
}

// one wave scans the 49 block sums -> exclusive offsets
__global__ __launch_bounds__(64) void tgd_scan2(const int* __restrict__ bsum,
                                                int* __restrict__ boff)
{
    int lane = threadIdx.x;
    int v = (lane < NSCANB) ? bsum[lane] : 0;
    int own = v;
    #pragma unroll
    for (int off = 1; off < 64; off <<= 1) {
        int t = __shfl_up(v, off);
        if (lane >= off) v += t;
    }
    if (lane < NSCANB) boff[lane] = v - own;
}

// add block offsets; produce ofs (exclusive) cursors
__global__ __launch_bounds__(1024) void tgd_scan3(const int* __restrict__ deg,
                                                  const int* __restrict__ boff,
                                                  int* __restrict__ rowptr,
                                                  int* __restrict__ ofs)
{
    const int i = blockIdx.x * 1024 + threadIdx.x;
    if (i < NNODES) {
        int r = rowptr[i + 1] + boff[blockIdx.x];
        rowptr[i + 1] = r;
        ofs[i] = r - deg[i];
    }
    if (i == 0) rowptr[0] = 0;
}

__global__ __launch_bounds__(256) void tgd_build(const int* __restrict__ ei,
                                                 int* __restrict__ ofs,
                                                 int* __restrict__ csr)
{
    int t = blockIdx.x * 256 + threadIdx.x;
    if (t >= NEDGES) return;
    int src = ei[t];
    int dst = ei[NEDGES + t];
    int pos = atomicAdd(&ofs[dst], 1);
    csr[pos] = src;
}

// ---------------------------------------------------------------------------
// Fused per-dst aggregation: 1 wave per node. Lane l loads ushort4 at
// kv[src*256 + 4l]: lanes 0..31 hold k (4 ch each), 32..63 hold v.
// Head dot = 3 shfl_xor (8-lane groups); shfl_xor(32) ships w to v-lanes.
// ---------------------------------------------------------------------------
__global__ __launch_bounds__(256) void tgd_agg(
    const int* __restrict__ csr, const int* __restrict__ rowptr,
    const float* __restrict__ q, const unsigned short* __restrict__ kv,
    float* __restrict__ outp)
{
    const int node = blockIdx.x * 4 + (threadIdx.x >> 6);
    const int lane = threadIdx.x & 63;
    if (node >= NNODES) return;
    const int start = rowptr[node];
    const int end   = rowptr[node + 1];
    if (start == end) return;             // deg-0: out stays = skip

    const bool isK = (lane < 32);
    float4 qv = {0.f, 0.f, 0.f, 0.f};
    if (isK) qv = *reinterpret_cast<const float4*>(&q[(size_t)node * FDIM + lane * 4]);
    const float inv = 0.17677669529663687f;  // 1/sqrt(32)

    float  den = 0.0f;
    float4 acc = {0.f, 0.f, 0.f, 0.f};

    for (int base = start; base < end; base += 64) {
        const int cnt = min(64, end - base);
        int myid = (lane < cnt) ? csr[base + lane] : 0;

        int j = 0;
        for (; j + 1 < cnt; j += 2) {
            int s0 = __shfl(myid, j);
            int s1 = __shfl(myid, j + 1);
            ushort4 r0 = *reinterpret_cast<const ushort4*>(&kv[(size_t)s0 * 256 + lane * 4]);
            ushort4 r1 = *reinterpret_cast<const ushort4*>(&kv[(size_t)s1 * 256 + lane * 4]);

            float a0 = bf2f(r0.x), a1 = bf2f(r0.y), a2 = bf2f(r0.z), a3 = bf2f(r0.w);
            float b0 = bf2f(r1.x), b1 = bf2f(r1.y), b2 = bf2f(r1.z), b3 = bf2f(r1.w);

            float sA = qv.x*a0 + qv.y*a1 + qv.z*a2 + qv.w*a3;
            float sB = qv.x*b0 + qv.y*b1 + qv.z*b2 + qv.w*b3;
            sA += __shfl_xor(sA, 1);  sB += __shfl_xor(sB, 1);
            sA += __shfl_xor(sA, 2);  sB += __shfl_xor(sB, 2);
            sA += __shfl_xor(sA, 4);  sB += __shfl_xor(sB, 4);
            float wA = __expf(sA * inv);
            float wB = __expf(sB * inv);
            wA = __shfl_xor(wA, 32);
            wB = __shfl_xor(wB, 32);
            if (!isK) {
                den += wA + wB;
                acc.x += wA*a0 + wB*b0;
                acc.y += wA*a1 + wB*b1;
                acc.z += wA*a2 + wB*b2;
                acc.w += wA*a3 + wB*b3;
            }
        }
        if (j < cnt) {
            int s0 = __shfl(myid, j);
            ushort4 r0 = *reinterpret_cast<const ushort4*>(&kv[(size_t)s0 * 256 + lane * 4]);
            float a0 = bf2f(r0.x), a1 = bf2f(r0.y), a2 = bf2f(r0.z), a3 = bf2f(r0.w);
            float sA = qv.x*a0 + qv.y*a1 + qv.z*a2 + qv.w*a3;
            sA += __shfl_xor(sA, 1);
            sA += __shfl_xor(sA, 2);
            sA += __shfl_xor(sA, 4);
            float wA = __expf(sA * inv);
            wA = __shfl_xor(wA, 32);
            if (!isK) {
                den += wA;
                acc.x += wA*a0; acc.y += wA*a1; acc.z += wA*a2; acc.w += wA*a3;
            }
        }
    }

    if (!isK) {
        float invd = 1.0f / den;
        float4* o = reinterpret_cast<float4*>(&outp[(size_t)node * FDIM + (lane - 32) * 4]);
        float4 cur = *o;
        cur.x += acc.x * invd;
        cur.y += acc.y * invd;
        cur.z += acc.z * invd;
        cur.w += acc.w * invd;
        *o = cur;
    }
}

// ---------------------------------------------------------------------------
extern "C" void kernel_launch(void* const* d_in, const int* in_sizes, int n_in,
                              void* d_out, int out_size, void* d_ws, size_t ws_size,
                              hipStream_t stream) {
    const float* x   = (const float*)d_in[0];
    const int*   ei  = (const int*)  d_in[1];
    const float* Wq  = (const float*)d_in[2];
    const float* bq  = (const float*)d_in[3];
    const float* Wk  = (const float*)d_in[4];
    const float* bk  = (const float*)d_in[5];
    const float* Wv  = (const float*)d_in[6];
    const float* bv  = (const float*)d_in[7];
    const float* Wsk = (const float*)d_in[8];
    const float* bsk = (const float*)d_in[9];
    float* outp = (float*)d_out;

    float* ws = (float*)d_ws;
    float*          q   = ws;                                           // 25.6MB
    unsigned short* kv  = (unsigned short*)(q + (size_t)NNODES * FDIM); // 25.6MB
    unsigned short* xb  = kv + (size_t)NNODES * 256;                    // 12.8MB
    unsigned short* Wt2 = xb + (size_t)NNODES * FDIM;                   // 128KB
    int* deg    = (int*)(Wt2 + 4 * FDIM * FDIM);
    int* rowptr = deg + NNODES;            // N+1
    int* ofs    = rowptr + NNODES + 1;     // N
    int* csr    = ofs + NNODES;            // E
    int* bsum   = csr + NEDGES;            // 49
    int* boff   = bsum + NSCANB;           // 49

    hipMemsetAsync(deg, 0, (size_t)NNODES * sizeof(int), stream);

    tgd_cvt_x<<<(NNODES * FDIM / 8 + 255) / 256, 256, 0, stream>>>(x, xb);
    tgd_cvt_w<<<(4 * 8 * 4 * 64 + 255) / 256, 256, 0, stream>>>(Wq, Wk, Wv, Wsk, Wt2);

    tgd_gemm_mfma<<<(NNODES + 63) / 64, 512, 0, stream>>>(
        xb, Wt2, bq, bk, bv, bsk, q, kv, outp);

    tgd_hist<<<(NEDGES + 255) / 256, 256, 0, stream>>>(ei, deg);
    tgd_scan1<<<NSCANB, 1024, 0, stream>>>(deg, rowptr, bsum);
    tgd_scan2<<<1, 64, 0, stream>>>(bsum, boff);
    tgd_scan3<<<NSCANB, 1024, 0, stream>>>(deg, boff, rowptr, ofs);
    tgd_build<<<(NEDGES + 255) / 256, 256, 0, stream>>>(ei, ofs, csr);
    tgd_agg<<<(NNODES + 3) / 4, 256, 0, stream>>>(csr, rowptr, q, kv, outp);
}

// Round 12
// 310.438 us; speedup vs baseline: 2.5742x; 1.0766x over previous
//
#include <hip/hip_runtime.h>
#include <hip/hip_bf16.h>

#define NNODES 50000
#define NEDGES 800000
#define FDIM   128
#define NHEADS 4
#define NSCANB ((NNODES + 1023) / 1024)   // 49
#define NBLK   782                        // ceil(50000/64)
#define NT16   (NBLK * 4)                 // 16-row tiles incl. pad = 3128

typedef __attribute__((ext_vector_type(8))) short  bf16x8;
typedef __attribute__((ext_vector_type(4))) float  f32x4;

static __device__ __forceinline__ unsigned short f2bf(float f) {
    __hip_bfloat16 h = __float2bfloat16(f);
    return *reinterpret_cast<unsigned short*>(&h);
}
static __device__ __forceinline__ float bf2f(unsigned short u) {
    return __uint_as_float(((unsigned int)u) << 16);
}

// ---------------------------------------------------------------------------
// x -> A-fragment-ordered bf16:  xa[((gt*4+ks)*64 + lane)*8 + j]
//   = x[row][k]  with row = gt*16+(lane&15), k = ks*32+(lane>>4)*8+j.
// A wave's A-fragment load in the GEMM is then base + lane*16B (contiguous 1KB).
// Rows >= NNODES zero-padded.
// ---------------------------------------------------------------------------
__global__ __launch_bounds__(256) void tgd_cvt_xa(const float* __restrict__ x,
                                                  unsigned short* __restrict__ xa)
{
    int t = blockIdx.x * 256 + threadIdx.x;          // 0 .. NT16*4*64-1
    if (t >= NT16 * 4 * 64) return;
    int lane = t & 63;
    int ks   = (t >> 6) & 3;
    int gt   = t >> 8;
    int row  = gt * 16 + (lane & 15);
    int k0   = ks * 32 + (lane >> 4) * 8;
    unsigned short u[8];
    if (row < NNODES) {
        float4 f0 = *reinterpret_cast<const float4*>(&x[(size_t)row * FDIM + k0]);
        float4 f1 = *reinterpret_cast<const float4*>(&x[(size_t)row * FDIM + k0 + 4]);
        u[0]=f2bf(f0.x); u[1]=f2bf(f0.y); u[2]=f2bf(f0.z); u[3]=f2bf(f0.w);
        u[4]=f2bf(f1.x); u[5]=f2bf(f1.y); u[6]=f2bf(f1.z); u[7]=f2bf(f1.w);
    } else {
        #pragma unroll
        for (int j = 0; j < 8; ++j) u[j] = 0;
    }
    *reinterpret_cast<uint4*>(&xa[(size_t)t * 8]) = *reinterpret_cast<uint4*>(u);
}

// ---------------------------------------------------------------------------
// Weights -> fragment-ordered bf16 (as round 11): one coalesced 1KB block
// per (m, ct, ks) B-fragment.
// ---------------------------------------------------------------------------
__global__ __launch_bounds__(256) void tgd_cvt_w(
    const float* __restrict__ Wq, const float* __restrict__ Wk,
    const float* __restrict__ Wv, const float* __restrict__ Wsk,
    unsigned short* __restrict__ Wt2)
{
    int t = blockIdx.x * 256 + threadIdx.x;   // 0..8191
    if (t >= 4 * 8 * 4 * 64) return;
    int m    = t >> 11;
    int ct   = (t >> 8) & 7;
    int ks   = (t >> 6) & 3;
    int lane = t & 63;
    int c  = ct * 16 + (lane & 15);
    int k0 = ks * 32 + (lane >> 4) * 8;
    const float* W = (m == 0) ? Wq : (m == 1) ? Wk : (m == 2) ? Wv : Wsk;
    unsigned short u[8];
    #pragma unroll
    for (int j = 0; j < 8; ++j)
        u[j] = f2bf(W[(size_t)(k0 + j) * FDIM + c]);
    *reinterpret_cast<uint4*>(&Wt2[(size_t)t * 8]) = *reinterpret_cast<uint4*>(u);
}

// ---------------------------------------------------------------------------
// MFMA GEMM with LDS-staged, fully-coalesced epilogue.
// 512 threads (8 waves), 64 rows/block. A from xa, B from Wt2 (both
// fragment-ordered, contiguous loads). Outputs staged per-matrix in a 32KB
// LDS tile and streamed out as contiguous float4/uint4 bursts.
// ---------------------------------------------------------------------------
__global__ __launch_bounds__(512) void tgd_gemm_mfma(
    const unsigned short* __restrict__ xa, const unsigned short* __restrict__ Wt2,
    const float* __restrict__ bq, const float* __restrict__ bk,
    const float* __restrict__ bv, const float* __restrict__ bsk,
    float* __restrict__ q, unsigned short* __restrict__ kv,
    float* __restrict__ outp)
{
    __shared__ float st[64 * 128];                      // 32KB staging
    unsigned short* sth = (unsigned short*)st;          // aliased bf16 [64][256]

    const int tid  = threadIdx.x;
    const int wave = tid >> 6, lane = tid & 63;
    const int mp   = wave >> 2;           // 0: (q,k)  1: (v,skip)
    const int wr   = wave & 3;
    const int l16  = lane & 15, lhi = lane >> 4;
    const int gt   = blockIdx.x * 4 + wr; // 16-row tile id
    const int base = blockIdx.x * 64;     // first row of block

    // A fragments: contiguous 1KB per (gt, ks)
    bf16x8 a[4];
    #pragma unroll
    for (int ks = 0; ks < 4; ++ks)
        a[ks] = *reinterpret_cast<const bf16x8*>(
            xa + ((size_t)(gt * 4 + ks) * 64 + lane) * 8);

    f32x4 acc[2][8];
    #pragma unroll
    for (int m2 = 0; m2 < 2; ++m2)
        #pragma unroll
        for (int ct = 0; ct < 8; ++ct)
            acc[m2][ct] = (f32x4){0.f, 0.f, 0.f, 0.f};

    #pragma unroll
    for (int ks = 0; ks < 4; ++ks) {
        #pragma unroll
        for (int m2 = 0; m2 < 2; ++m2) {
            const int m = mp * 2 + m2;
            const unsigned short* wb =
                Wt2 + ((size_t)((m * 8 * 4 + ks) * 64) + lane) * 8;
            #pragma unroll
            for (int ct = 0; ct < 8; ++ct) {
                bf16x8 b = *reinterpret_cast<const bf16x8*>(wb + (size_t)ct * 2048);
                acc[m2][ct] = __builtin_amdgcn_mfma_f32_16x16x32_bf16(
                    a[ks], b, acc[m2][ct], 0, 0, 0);
            }
        }
    }

    const int rowl0 = wr * 16 + lhi * 4;   // this thread's first LDS row

    // ---- phase 1: q (waves 0-3) ----
    if (mp == 0) {
        #pragma unroll
        for (int ct = 0; ct < 8; ++ct) {
            int col = ct * 16 + l16;
            float bval = bq[col];
            #pragma unroll
            for (int r = 0; r < 4; ++r)
                st[(rowl0 + r) * 128 + col] = acc[0][ct][r] + bval;
        }
    }
    __syncthreads();
    #pragma unroll
    for (int i = 0; i < 4; ++i) {
        int idx = i * 512 + tid;           // float4 index in [64][32]
        int row = idx >> 5, c4 = idx & 31;
        if (base + row < NNODES)
            *reinterpret_cast<float4*>(&q[(size_t)(base + row) * FDIM + c4 * 4]) =
                *reinterpret_cast<const float4*>(&st[row * 128 + c4 * 4]);
    }
    __syncthreads();

    // ---- phase 2: skip -> outp (waves 4-7) ----
    if (mp == 1) {
        #pragma unroll
        for (int ct = 0; ct < 8; ++ct) {
            int col = ct * 16 + l16;
            float bval = bsk[col];
            #pragma unroll
            for (int r = 0; r < 4; ++r)
                st[(rowl0 + r) * 128 + col] = acc[1][ct][r] + bval;
        }
    }
    __syncthreads();
    #pragma unroll
    for (int i = 0; i < 4; ++i) {
        int idx = i * 512 + tid;
        int row = idx >> 5, c4 = idx & 31;
        if (base + row < NNODES)
            *reinterpret_cast<float4*>(&outp[(size_t)(base + row) * FDIM + c4 * 4]) =
                *reinterpret_cast<const float4*>(&st[row * 128 + c4 * 4]);
    }
    __syncthreads();

    // ---- phase 3: k | v -> kv bf16 [64][256] ----
    {
        const int off  = (mp == 0) ? 0 : 128;           // k in cols 0-127, v in 128-255
        const int m2s  = (mp == 0) ? 1 : 0;             // k = acc[1] (mp0), v = acc[0] (mp1)
        const float* bias = (mp == 0) ? bk : bv;
        #pragma unroll
        for (int ct = 0; ct < 8; ++ct) {
            int col = ct * 16 + l16;
            float bval = bias[col];
            #pragma unroll
            for (int r = 0; r < 4; ++r)
                sth[(rowl0 + r) * 256 + off + col] = f2bf(acc[m2s][ct][r] + bval);
        }
    }
    __syncthreads();
    #pragma unroll
    for (int i = 0; i < 4; ++i) {
        int idx = i * 512 + tid;           // uint4 (8 ush) index in [64][32]
        int row = idx >> 5, c8 = idx & 31;
        if (base + row < NNODES)
            *reinterpret_cast<uint4*>(&kv[(size_t)(base + row) * 256 + c8 * 8]) =
                *reinterpret_cast<const uint4*>(&sth[row * 256 + c8 * 8]);
    }
}

// ---------------------------------------------------------------------------
// CSR build: histogram -> hierarchical scan -> scatter src ids
// ---------------------------------------------------------------------------
__global__ __launch_bounds__(256) void tgd_hist(const int* __restrict__ ei,
                                                int* __restrict__ deg)
{
    int t = blockIdx.x * 256 + threadIdx.x;
    if (t < NEDGES) atomicAdd(&deg[ei[NEDGES + t]], 1);
}

__global__ __launch_bounds__(1024) void tgd_scan1(const int* __restrict__ deg,
                                                  int* __restrict__ rowptr,
                                                  int* __restrict__ bsum)
{
    __shared__ int buf[1024];
    const int tid = threadIdx.x;
    const int i   = blockIdx.x * 1024 + tid;
    int d = (i < NNODES) ? deg[i] : 0;
    buf[tid] = d;
    __syncthreads();
    #pragma unroll
    for (int off = 1; off < 1024; off <<= 1) {
        int t2 = (tid >= off) ? buf[tid - off] : 0;
        __syncthreads();
        buf[tid] += t2;
        __syncthreads();
    }
    if (i < NNODES) rowptr[i + 1] = buf[tid];
    if (tid == 1023) bsum[blockIdx.x] = buf[1023];
}

__global__ __launch_bounds__(64) void tgd_scan2(const int* __restrict__ bsum,
                                                int* __restrict__ boff)
{
    int lane = threadIdx.x;
    int v = (lane < NSCANB) ? bsum[lane] : 0;
    int own = v;
    #pragma unroll
    for (int off = 1; off < 64; off <<= 1) {
        int t = __shfl_up(v, off);
        if (lane >= off) v += t;
    }
    if (lane < NSCANB) boff[lane] = v - own;
}

__global__ __launch_bounds__(1024) void tgd_scan3(const int* __restrict__ deg,
                                                  const int* __restrict__ boff,
                                                  int* __restrict__ rowptr,
                                                  int* __restrict__ ofs)
{
    const int i = blockIdx.x * 1024 + threadIdx.x;
    if (i < NNODES) {
        int r = rowptr[i + 1] + boff[blockIdx.x];
        rowptr[i + 1] = r;
        ofs[i] = r - deg[i];
    }
    if (i == 0) rowptr[0] = 0;
}

__global__ __launch_bounds__(256) void tgd_build(const int* __restrict__ ei,
                                                 int* __restrict__ ofs,
                                                 int* __restrict__ csr)
{
    int t = blockIdx.x * 256 + threadIdx.x;
    if (t >= NEDGES) return;
    int src = ei[t];
    int dst = ei[NEDGES + t];
    int pos = atomicAdd(&ofs[dst], 1);
    csr[pos] = src;
}

// ---------------------------------------------------------------------------
// Fused per-dst aggregation (unchanged from round 10, verified 80-90us).
// ---------------------------------------------------------------------------
__global__ __launch_bounds__(256) void tgd_agg(
    const int* __restrict__ csr, const int* __restrict__ rowptr,
    const float* __restrict__ q, const unsigned short* __restrict__ kv,
    float* __restrict__ outp)
{
    const int node = blockIdx.x * 4 + (threadIdx.x >> 6);
    const int lane = threadIdx.x & 63;
    if (node >= NNODES) return;
    const int start = rowptr[node];
    const int end   = rowptr[node + 1];
    if (start == end) return;

    const bool isK = (lane < 32);
    float4 qv = {0.f, 0.f, 0.f, 0.f};
    if (isK) qv = *reinterpret_cast<const float4*>(&q[(size_t)node * FDIM + lane * 4]);
    const float inv = 0.17677669529663687f;  // 1/sqrt(32)

    float  den = 0.0f;
    float4 acc = {0.f, 0.f, 0.f, 0.f};

    for (int base = start; base < end; base += 64) {
        const int cnt = min(64, end - base);
        int myid = (lane < cnt) ? csr[base + lane] : 0;

        int j = 0;
        for (; j + 1 < cnt; j += 2) {
            int s0 = __shfl(myid, j);
            int s1 = __shfl(myid, j + 1);
            ushort4 r0 = *reinterpret_cast<const ushort4*>(&kv[(size_t)s0 * 256 + lane * 4]);
            ushort4 r1 = *reinterpret_cast<const ushort4*>(&kv[(size_t)s1 * 256 + lane * 4]);

            float a0 = bf2f(r0.x), a1 = bf2f(r0.y), a2 = bf2f(r0.z), a3 = bf2f(r0.w);
            float b0 = bf2f(r1.x), b1 = bf2f(r1.y), b2 = bf2f(r1.z), b3 = bf2f(r1.w);

            float sA = qv.x*a0 + qv.y*a1 + qv.z*a2 + qv.w*a3;
            float sB = qv.x*b0 + qv.y*b1 + qv.z*b2 + qv.w*b3;
            sA += __shfl_xor(sA, 1);  sB += __shfl_xor(sB, 1);
            sA += __shfl_xor(sA, 2);  sB += __shfl_xor(sB, 2);
            sA += __shfl_xor(sA, 4);  sB += __shfl_xor(sB, 4);
            float wA = __expf(sA * inv);
            float wB = __expf(sB * inv);
            wA = __shfl_xor(wA, 32);
            wB = __shfl_xor(wB, 32);
            if (!isK) {
                den += wA + wB;
                acc.x += wA*a0 + wB*b0;
                acc.y += wA*a1 + wB*b1;
                acc.z += wA*a2 + wB*b2;
                acc.w += wA*a3 + wB*b3;
            }
        }
        if (j < cnt) {
            int s0 = __shfl(myid, j);
            ushort4 r0 = *reinterpret_cast<const ushort4*>(&kv[(size_t)s0 * 256 + lane * 4]);
            float a0 = bf2f(r0.x), a1 = bf2f(r0.y), a2 = bf2f(r0.z), a3 = bf2f(r0.w);
            float sA = qv.x*a0 + qv.y*a1 + qv.z*a2 + qv.w*a3;
            sA += __shfl_xor(sA, 1);
            sA += __shfl_xor(sA, 2);
            sA += __shfl_xor(sA, 4);
            float wA = __expf(sA * inv);
            wA = __shfl_xor(wA, 32);
            if (!isK) {
                den += wA;
                acc.x += wA*a0; acc.y += wA*a1; acc.z += wA*a2; acc.w += wA*a3;
            }
        }
    }

    if (!isK) {
        float invd = 1.0f / den;
        float4* o = reinterpret_cast<float4*>(&outp[(size_t)node * FDIM + (lane - 32) * 4]);
        float4 cur = *o;
        cur.x += acc.x * invd;
        cur.y += acc.y * invd;
        cur.z += acc.z * invd;
        cur.w += acc.w * invd;
        *o = cur;
    }
}

// ---------------------------------------------------------------------------
extern "C" void kernel_launch(void* const* d_in, const int* in_sizes, int n_in,
                              void* d_out, int out_size, void* d_ws, size_t ws_size,
                              hipStream_t stream) {
    const float* x   = (const float*)d_in[0];
    const int*   ei  = (const int*)  d_in[1];
    const float* Wq  = (const float*)d_in[2];
    const float* bq  = (const float*)d_in[3];
    const float* Wk  = (const float*)d_in[4];
    const float* bk  = (const float*)d_in[5];
    const float* Wv  = (const float*)d_in[6];
    const float* bv  = (const float*)d_in[7];
    const float* Wsk = (const float*)d_in[8];
    const float* bsk = (const float*)d_in[9];
    float* outp = (float*)d_out;

    float* ws = (float*)d_ws;
    float*          q   = ws;                                           // 25.6MB
    unsigned short* kv  = (unsigned short*)(q + (size_t)NNODES * FDIM); // 25.6MB
    unsigned short* xa  = kv + (size_t)NNODES * 256;                    // 12.82MB
    unsigned short* Wt2 = xa + (size_t)NT16 * 4 * 64 * 8;               // 128KB
    int* deg    = (int*)(Wt2 + 4 * FDIM * FDIM);
    int* rowptr = deg + NNODES;            // N+1
    int* ofs    = rowptr + NNODES + 1;     // N
    int* csr    = ofs + NNODES;            // E
    int* bsum   = csr + NEDGES;            // 49
    int* boff   = bsum + NSCANB;           // 49

    hipMemsetAsync(deg, 0, (size_t)NNODES * sizeof(int), stream);

    tgd_cvt_xa<<<(NT16 * 4 * 64 + 255) / 256, 256, 0, stream>>>(x, xa);
    tgd_cvt_w<<<(4 * 8 * 4 * 64 + 255) / 256, 256, 0, stream>>>(Wq, Wk, Wv, Wsk, Wt2);

    tgd_gemm_mfma<<<NBLK, 512, 0, stream>>>(
        xa, Wt2, bq, bk, bv, bsk, q, kv, outp);

    tgd_hist<<<(NEDGES + 255) / 256, 256, 0, stream>>>(ei, deg);
    tgd_scan1<<<NSCANB, 1024, 0, stream>>>(deg, rowptr, bsum);
    tgd_scan2<<<1, 64, 0, stream>>>(bsum, boff);
    tgd_scan3<<<NSCANB, 1024, 0, stream>>>(deg, boff, rowptr, ofs);
    tgd_build<<<(NEDGES + 255) / 256, 256, 0, stream>>>(ei, ofs, csr);
    tgd_agg<<<(NNODES + 3) / 4, 256, 0, stream>>>(csr, rowptr, q, kv, outp);
}

// Round 16
// 296.293 us; speedup vs baseline: 2.6970x; 1.0477x over previous
//
#include <hip/hip_runtime.h>
#include <hip/hip_bf16.h>

#define NNODES 50000
#define NEDGES 800000
#define FDIM   128
#define NHEADS 4
#define NSCANB ((NNODES + 1023) / 1024)   // 49
#define NBLK   782                        // ceil(50000/64)
#define NT16   (NBLK * 4)                 // 16-row tiles incl. pad = 3128
#define NFULL  3125                       // 50000/16 exactly: tiles >= NFULL are pad

typedef __attribute__((ext_vector_type(8))) short  bf16x8;
typedef __attribute__((ext_vector_type(4))) float  f32x4;

static __device__ __forceinline__ unsigned short f2bf(float f) {
    __hip_bfloat16 h = __float2bfloat16(f);
    return *reinterpret_cast<unsigned short*>(&h);
}
static __device__ __forceinline__ float bf2f(unsigned short u) {
    return __uint_as_float(((unsigned int)u) << 16);
}

// ---------------------------------------------------------------------------
// x -> A-fragment-ordered bf16 via LDS staging.
// Block b handles tile gt=b (16 rows x 128 cols = one contiguous 8KB span of x).
// Read coalesced, stage bf16 in LDS (stride 136 to spread banks), write
// fragment-ordered: xa[((gt*4+ks)*64+lane)*8+j] = x[gt*16+(lane&15)][ks*32+(lane>>4)*8+j]
// ---------------------------------------------------------------------------
__global__ __launch_bounds__(256) void tgd_cvt_xa(const float* __restrict__ x,
                                                  unsigned short* __restrict__ xa)
{
    __shared__ unsigned short lds[16 * 136];
    const int gt  = blockIdx.x;
    const int tid = threadIdx.x;

    if (gt < NFULL) {
        const float* src = x + (size_t)gt * 2048 + tid * 8;
        float4 f0 = *reinterpret_cast<const float4*>(src);
        float4 f1 = *reinterpret_cast<const float4*>(src + 4);
        const int row = tid >> 4;              // (tid*8)>>7
        const int col = (tid & 15) * 8;
        unsigned short* d = &lds[row * 136 + col];
        d[0]=f2bf(f0.x); d[1]=f2bf(f0.y); d[2]=f2bf(f0.z); d[3]=f2bf(f0.w);
        d[4]=f2bf(f1.x); d[5]=f2bf(f1.y); d[6]=f2bf(f1.z); d[7]=f2bf(f1.w);
    }
    __syncthreads();

    const int lane = tid & 63;
    const int ks   = tid >> 6;
    const int row  = lane & 15;
    const int k0   = ks * 32 + (lane >> 4) * 8;
    unsigned short u[8];
    if (gt < NFULL) {
        #pragma unroll
        for (int j = 0; j < 8; ++j) u[j] = lds[row * 136 + k0 + j];
    } else {
        #pragma unroll
        for (int j = 0; j < 8; ++j) u[j] = 0;
    }
    *reinterpret_cast<uint4*>(&xa[((size_t)gt * 256 + tid) * 8]) =
        *reinterpret_cast<uint4*>(u);
}

// ---------------------------------------------------------------------------
// Weights -> fragment-ordered bf16: one coalesced 1KB block per (m,ct,ks).
// ---------------------------------------------------------------------------
__global__ __launch_bounds__(256) void tgd_cvt_w(
    const float* __restrict__ Wq, const float* __restrict__ Wk,
    const float* __restrict__ Wv, const float* __restrict__ Wsk,
    unsigned short* __restrict__ Wt2)
{
    int t = blockIdx.x * 256 + threadIdx.x;   // 0..8191
    if (t >= 4 * 8 * 4 * 64) return;
    int m    = t >> 11;
    int ct   = (t >> 8) & 7;
    int ks   = (t >> 6) & 3;
    int lane = t & 63;
    int c  = ct * 16 + (lane & 15);
    int k0 = ks * 32 + (lane >> 4) * 8;
    const float* W = (m == 0) ? Wq : (m == 1) ? Wk : (m == 2) ? Wv : Wsk;
    unsigned short u[8];
    #pragma unroll
    for (int j = 0; j < 8; ++j)
        u[j] = f2bf(W[(size_t)(k0 + j) * FDIM + c]);
    *reinterpret_cast<uint4*>(&Wt2[(size_t)t * 8]) = *reinterpret_cast<uint4*>(u);
}

// ---------------------------------------------------------------------------
// MFMA GEMM, LDS-staged coalesced epilogue. q stored as bf16 (qb).
// ---------------------------------------------------------------------------
__global__ __launch_bounds__(512) void tgd_gemm_mfma(
    const unsigned short* __restrict__ xa, const unsigned short* __restrict__ Wt2,
    const float* __restrict__ bq, const float* __restrict__ bk,
    const float* __restrict__ bv, const float* __restrict__ bsk,
    unsigned short* __restrict__ qb, unsigned short* __restrict__ kv,
    float* __restrict__ outp)
{
    __shared__ float st[64 * 128];                      // 32KB staging
    unsigned short* sth = (unsigned short*)st;

    const int tid  = threadIdx.x;
    const int wave = tid >> 6, lane = tid & 63;
    const int mp   = wave >> 2;           // 0: (q,k)  1: (v,skip)
    const int wr   = wave & 3;
    const int l16  = lane & 15, lhi = lane >> 4;
    const int gt   = blockIdx.x * 4 + wr;
    const int base = blockIdx.x * 64;

    bf16x8 a[4];
    #pragma unroll
    for (int ks = 0; ks < 4; ++ks)
        a[ks] = *reinterpret_cast<const bf16x8*>(
            xa + ((size_t)(gt * 4 + ks) * 64 + lane) * 8);

    f32x4 acc[2][8];
    #pragma unroll
    for (int m2 = 0; m2 < 2; ++m2)
        #pragma unroll
        for (int ct = 0; ct < 8; ++ct)
            acc[m2][ct] = (f32x4){0.f, 0.f, 0.f, 0.f};

    #pragma unroll
    for (int ks = 0; ks < 4; ++ks) {
        #pragma unroll
        for (int m2 = 0; m2 < 2; ++m2) {
            const int m = mp * 2 + m2;
            const unsigned short* wb =
                Wt2 + ((size_t)((m * 8 * 4 + ks) * 64) + lane) * 8;
            #pragma unroll
            for (int ct = 0; ct < 8; ++ct) {
                bf16x8 b = *reinterpret_cast<const bf16x8*>(wb + (size_t)ct * 2048);
                acc[m2][ct] = __builtin_amdgcn_mfma_f32_16x16x32_bf16(
                    a[ks], b, acc[m2][ct], 0, 0, 0);
            }
        }
    }

    const int rowl0 = wr * 16 + lhi * 4;

    // ---- phase 1: q -> qb (bf16) ----
    if (mp == 0) {
        #pragma unroll
        for (int ct = 0; ct < 8; ++ct) {
            int col = ct * 16 + l16;
            float bval = bq[col];
            #pragma unroll
            for (int r = 0; r < 4; ++r)
                sth[(rowl0 + r) * 128 + col] = f2bf(acc[0][ct][r] + bval);
        }
    }
    __syncthreads();
    #pragma unroll
    for (int i = 0; i < 2; ++i) {
        int idx = i * 512 + tid;           // uint4 idx in [64][16]
        int row = idx >> 4, c8 = idx & 15;
        if (base + row < NNODES)
            *reinterpret_cast<uint4*>(&qb[(size_t)(base + row) * 128 + c8 * 8]) =
                *reinterpret_cast<const uint4*>(&sth[row * 128 + c8 * 8]);
    }
    __syncthreads();

    // ---- phase 2: skip -> outp (fp32) ----
    if (mp == 1) {
        #pragma unroll
        for (int ct = 0; ct < 8; ++ct) {
            int col = ct * 16 + l16;
            float bval = bsk[col];
            #pragma unroll
            for (int r = 0; r < 4; ++r)
                st[(rowl0 + r) * 128 + col] = acc[1][ct][r] + bval;
        }
    }
    __syncthreads();
    #pragma unroll
    for (int i = 0; i < 4; ++i) {
        int idx = i * 512 + tid;
        int row = idx >> 5, c4 = idx & 31;
        if (base + row < NNODES)
            *reinterpret_cast<float4*>(&outp[(size_t)(base + row) * FDIM + c4 * 4]) =
                *reinterpret_cast<const float4*>(&st[row * 128 + c4 * 4]);
    }
    __syncthreads();

    // ---- phase 3: k | v -> kv bf16 [64][256] ----
    {
        const int off  = (mp == 0) ? 0 : 128;
        const int m2s  = (mp == 0) ? 1 : 0;
        const float* bias = (mp == 0) ? bk : bv;
        #pragma unroll
        for (int ct = 0; ct < 8; ++ct) {
            int col = ct * 16 + l16;
            float bval = bias[col];
            #pragma unroll
            for (int r = 0; r < 4; ++r)
                sth[(rowl0 + r) * 256 + off + col] = f2bf(acc[m2s][ct][r] + bval);
        }
    }
    __syncthreads();
    #pragma unroll
    for (int i = 0; i < 4; ++i) {
        int idx = i * 512 + tid;
        int row = idx >> 5, c8 = idx & 31;
        if (base + row < NNODES)
            *reinterpret_cast<uint4*>(&kv[(size_t)(base + row) * 256 + c8 * 8]) =
                *reinterpret_cast<const uint4*>(&sth[row * 256 + c8 * 8]);
    }
}

// ---------------------------------------------------------------------------
// CSR build: histogram -> hierarchical scan -> scatter src ids
// ---------------------------------------------------------------------------
__global__ __launch_bounds__(256) void tgd_hist(const int* __restrict__ ei,
                                                int* __restrict__ deg)
{
    int t = blockIdx.x * 256 + threadIdx.x;
    if (t < NEDGES) atomicAdd(&deg[ei[NEDGES + t]], 1);
}

__global__ __launch_bounds__(1024) void tgd_scan1(const int* __restrict__ deg,
                                                  int* __restrict__ rowptr,
                                                  int* __restrict__ bsum)
{
    __shared__ int buf[1024];
    const int tid = threadIdx.x;
    const int i   = blockIdx.x * 1024 + tid;
    int d = (i < NNODES) ? deg[i] : 0;
    buf[tid] = d;
    __syncthreads();
    #pragma unroll
    for (int off = 1; off < 1024; off <<= 1) {
        int t2 = (tid >= off) ? buf[tid - off] : 0;
        __syncthreads();
        buf[tid] += t2;
        __syncthreads();
    }
    if (i < NNODES) rowptr[i + 1] = buf[tid];
    if (tid == 1023) bsum[blockIdx.x] = buf[1023];
}

__global__ __launch_bounds__(64) void tgd_scan2(const int* __restrict__ bsum,
                                                int* __restrict__ boff)
{
    int lane = threadIdx.x;
    int v = (lane < NSCANB) ? bsum[lane] : 0;
    int own = v;
    #pragma unroll
    for (int off = 1; off < 64; off <<= 1) {
        int t = __shfl_up(v, off);
        if (lane >= off) v += t;
    }
    if (lane < NSCANB) boff[lane] = v - own;
}

__global__ __launch_bounds__(1024) void tgd_scan3(const int* __restrict__ deg,
                                                  const int* __restrict__ boff,
                                                  int* __restrict__ rowptr,
                                                  int* __restrict__ ofs)
{
    const int i = blockIdx.x * 1024 + threadIdx.x;
    if (i < NNODES) {
        int r = rowptr[i + 1] + boff[blockIdx.x];
        rowptr[i + 1] = r;
        ofs[i] = r - deg[i];
    }
    if (i == 0) rowptr[0] = 0;
}

__global__ __launch_bounds__(256) void tgd_build(const int* __restrict__ ei,
                                                 int* __restrict__ ofs,
                                                 int* __restrict__ csr)
{
    int t = blockIdx.x * 256 + threadIdx.x;
    if (t >= NEDGES) return;
    int src = ei[t];
    int dst = ei[NEDGES + t];
    int pos = atomicAdd(&ofs[dst], 1);
    csr[pos] = src;
}

// ---------------------------------------------------------------------------
// Fused per-dst aggregation: 1 wave per node, unroll-4 (4 gathers in flight).
// Lane l loads ushort4 at kv[src*256+4l]: lanes 0..31 k, 32..63 v.
// ---------------------------------------------------------------------------
__global__ __launch_bounds__(256) void tgd_agg(
    const int* __restrict__ csr, const int* __restrict__ rowptr,
    const unsigned short* __restrict__ qb, const unsigned short* __restrict__ kv,
    float* __restrict__ outp)
{
    const int node = blockIdx.x * 4 + (threadIdx.x >> 6);
    const int lane = threadIdx.x & 63;
    if (node >= NNODES) return;
    const int start = rowptr[node];
    const int end   = rowptr[node + 1];
    if (start == end) return;

    const bool isK = (lane < 32);
    float4 qv = {0.f, 0.f, 0.f, 0.f};
    if (isK) {
        ushort4 qu = *reinterpret_cast<const ushort4*>(&qb[(size_t)node * FDIM + lane * 4]);
        qv.x = bf2f(qu.x); qv.y = bf2f(qu.y); qv.z = bf2f(qu.z); qv.w = bf2f(qu.w);
    }
    const float inv = 0.17677669529663687f;  // 1/sqrt(32)

    float  den = 0.0f;
    float4 acc = {0.f, 0.f, 0.f, 0.f};

    for (int base = start; base < end; base += 64) {
        const int cnt = min(64, end - base);
        int myid = (lane < cnt) ? csr[base + lane] : 0;

        int j = 0;
        for (; j + 3 < cnt; j += 4) {
            int s0 = __shfl(myid, j);
            int s1 = __shfl(myid, j + 1);
            int s2 = __shfl(myid, j + 2);
            int s3 = __shfl(myid, j + 3);
            ushort4 r0 = *reinterpret_cast<const ushort4*>(&kv[(size_t)s0 * 256 + lane * 4]);
            ushort4 r1 = *reinterpret_cast<const ushort4*>(&kv[(size_t)s1 * 256 + lane * 4]);
            ushort4 r2 = *reinterpret_cast<const ushort4*>(&kv[(size_t)s2 * 256 + lane * 4]);
            ushort4 r3 = *reinterpret_cast<const ushort4*>(&kv[(size_t)s3 * 256 + lane * 4]);

            float a0 = bf2f(r0.x), a1 = bf2f(r0.y), a2 = bf2f(r0.z), a3 = bf2f(r0.w);
            float b0 = bf2f(r1.x), b1 = bf2f(r1.y), b2 = bf2f(r1.z), b3 = bf2f(r1.w);
            float c0 = bf2f(r2.x), c1 = bf2f(r2.y), c2 = bf2f(r2.z), c3 = bf2f(r2.w);
            float d0 = bf2f(r3.x), d1 = bf2f(r3.y), d2 = bf2f(r3.z), d3 = bf2f(r3.w);

            float sA = qv.x*a0 + qv.y*a1 + qv.z*a2 + qv.w*a3;
            float sB = qv.x*b0 + qv.y*b1 + qv.z*b2 + qv.w*b3;
            float sC = qv.x*c0 + qv.y*c1 + qv.z*c2 + qv.w*c3;
            float sD = qv.x*d0 + qv.y*d1 + qv.z*d2 + qv.w*d3;
            sA += __shfl_xor(sA, 1);  sB += __shfl_xor(sB, 1);
            sC += __shfl_xor(sC, 1);  sD += __shfl_xor(sD, 1);
            sA += __shfl_xor(sA, 2);  sB += __shfl_xor(sB, 2);
            sC += __shfl_xor(sC, 2);  sD += __shfl_xor(sD, 2);
            sA += __shfl_xor(sA, 4);  sB += __shfl_xor(sB, 4);
            sC += __shfl_xor(sC, 4);  sD += __shfl_xor(sD, 4);
            float wA = __expf(sA * inv);
            float wB = __expf(sB * inv);
            float wC = __expf(sC * inv);
            float wD = __expf(sD * inv);
            wA = __shfl_xor(wA, 32);
            wB = __shfl_xor(wB, 32);
            wC = __shfl_xor(wC, 32);
            wD = __shfl_xor(wD, 32);
            if (!isK) {
                den += (wA + wB) + (wC + wD);
                acc.x += wA*a0 + wB*b0 + wC*c0 + wD*d0;
                acc.y += wA*a1 + wB*b1 + wC*c1 + wD*d1;
                acc.z += wA*a2 + wB*b2 + wC*c2 + wD*d2;
                acc.w += wA*a3 + wB*b3 + wC*c3 + wD*d3;
            }
        }
        for (; j + 1 < cnt; j += 2) {
            int s0 = __shfl(myid, j);
            int s1 = __shfl(myid, j + 1);
            ushort4 r0 = *reinterpret_cast<const ushort4*>(&kv[(size_t)s0 * 256 + lane * 4]);
            ushort4 r1 = *reinterpret_cast<const ushort4*>(&kv[(size_t)s1 * 256 + lane * 4]);
            float a0 = bf2f(r0.x), a1 = bf2f(r0.y), a2 = bf2f(r0.z), a3 = bf2f(r0.w);
            float b0 = bf2f(r1.x), b1 = bf2f(r1.y), b2 = bf2f(r1.z), b3 = bf2f(r1.w);
            float sA = qv.x*a0 + qv.y*a1 + qv.z*a2 + qv.w*a3;
            float sB = qv.x*b0 + qv.y*b1 + qv.z*b2 + qv.w*b3;
            sA += __shfl_xor(sA, 1);  sB += __shfl_xor(sB, 1);
            sA += __shfl_xor(sA, 2);  sB += __shfl_xor(sB, 2);
            sA += __shfl_xor(sA, 4);  sB += __shfl_xor(sB, 4);
            float wA = __expf(sA * inv);
            float wB = __expf(sB * inv);
            wA = __shfl_xor(wA, 32);
            wB = __shfl_xor(wB, 32);
            if (!isK) {
                den += wA + wB;
                acc.x += wA*a0 + wB*b0;
                acc.y += wA*a1 + wB*b1;
                acc.z += wA*a2 + wB*b2;
                acc.w += wA*a3 + wB*b3;
            }
        }
        if (j < cnt) {
            int s0 = __shfl(myid, j);
            ushort4 r0 = *reinterpret_cast<const ushort4*>(&kv[(size_t)s0 * 256 + lane * 4]);
            float a0 = bf2f(r0.x), a1 = bf2f(r0.y), a2 = bf2f(r0.z), a3 = bf2f(r0.w);
            float sA = qv.x*a0 + qv.y*a1 + qv.z*a2 + qv.w*a3;
            sA += __shfl_xor(sA, 1);
            sA += __shfl_xor(sA, 2);
            sA += __shfl_xor(sA, 4);
            float wA = __expf(sA * inv);
            wA = __shfl_xor(wA, 32);
            if (!isK) {
                den += wA;
                acc.x += wA*a0; acc.y += wA*a1; acc.z += wA*a2; acc.w += wA*a3;
            }
        }
    }

    if (!isK) {
        float invd = 1.0f / den;
        float4* o = reinterpret_cast<float4*>(&outp[(size_t)node * FDIM + (lane - 32) * 4]);
        float4 cur = *o;
        cur.x += acc.x * invd;
        cur.y += acc.y * invd;
        cur.z += acc.z * invd;
        cur.w += acc.w * invd;
        *o = cur;
    }
}

// ---------------------------------------------------------------------------
extern "C" void kernel_launch(void* const* d_in, const int* in_sizes, int n_in,
                              void* d_out, int out_size, void* d_ws, size_t ws_size,
                              hipStream_t stream) {
    const float* x   = (const float*)d_in[0];
    const int*   ei  = (const int*)  d_in[1];
    const float* Wq  = (const float*)d_in[2];
    const float* bq  = (const float*)d_in[3];
    const float* Wk  = (const float*)d_in[4];
    const float* bk  = (const float*)d_in[5];
    const float* Wv  = (const float*)d_in[6];
    const float* bv  = (const float*)d_in[7];
    const float* Wsk = (const float*)d_in[8];
    const float* bsk = (const float*)d_in[9];
    float* outp = (float*)d_out;

    unsigned short* qb  = (unsigned short*)d_ws;                    // N*128 bf16 (12.8MB)
    unsigned short* kv  = qb + (size_t)NNODES * FDIM;               // N*256 bf16 (25.6MB)
    unsigned short* xa  = kv + (size_t)NNODES * 256;                // NT16*2048 (12.8MB)
    unsigned short* Wt2 = xa + (size_t)NT16 * 2048;                 // 128KB
    int* deg    = (int*)(Wt2 + 4 * FDIM * FDIM);
    int* rowptr = deg + NNODES;            // N+1
    int* ofs    = rowptr + NNODES + 1;     // N
    int* csr    = ofs + NNODES;            // E
    int* bsum   = csr + NEDGES;            // 49
    int* boff   = bsum + NSCANB;           // 49

    hipMemsetAsync(deg, 0, (size_t)NNODES * sizeof(int), stream);

    tgd_cvt_xa<<<NT16, 256, 0, stream>>>(x, xa);
    tgd_cvt_w<<<(4 * 8 * 4 * 64 + 255) / 256, 256, 0, stream>>>(Wq, Wk, Wv, Wsk, Wt2);

    tgd_gemm_mfma<<<NBLK, 512, 0, stream>>>(
        xa, Wt2, bq, bk, bv, bsk, qb, kv, outp);

    tgd_hist<<<(NEDGES + 255) / 256, 256, 0, stream>>>(ei, deg);
    tgd_scan1<<<NSCANB, 1024, 0, stream>>>(deg, rowptr, bsum);
    tgd_scan2<<<1, 64, 0, stream>>>(bsum, boff);
    tgd_scan3<<<NSCANB, 1024, 0, stream>>>(deg, boff, rowptr, ofs);
    tgd_build<<<(NEDGES + 255) / 256, 256, 0, stream>>>(ei, ofs, csr);
    tgd_agg<<<(NNODES + 3) / 4, 256, 0, stream>>>(csr, rowptr, qb, kv, outp);
}

// Round 17
// 274.984 us; speedup vs baseline: 2.9061x; 1.0775x over previous
//
#include <hip/hip_runtime.h>
#include <hip/hip_bf16.h>

#define NNODES 50000
#define NEDGES 800000
#define FDIM   128
#define NHEADS 4
#define NSCANB ((NNODES + 1023) / 1024)   // 49
#define NBLK   782                        // ceil(50000/64)

typedef __attribute__((ext_vector_type(8))) short  bf16x8;
typedef __attribute__((ext_vector_type(4))) float  f32x4;

static __device__ __forceinline__ unsigned short f2bf(float f) {
    __hip_bfloat16 h = __float2bfloat16(f);
    return *reinterpret_cast<unsigned short*>(&h);
}
static __device__ __forceinline__ float bf2f(unsigned short u) {
    return __uint_as_float(((unsigned int)u) << 16);
}

// ---------------------------------------------------------------------------
// prep: blocks 0..31 -> weights to fragment-ordered bf16 (one coalesced 1KB
// block per (m,ct,ks) B-fragment); blocks 32..80 -> zero deg.
// ---------------------------------------------------------------------------
__global__ __launch_bounds__(256) void tgd_prep(
    const float* __restrict__ Wq, const float* __restrict__ Wk,
    const float* __restrict__ Wv, const float* __restrict__ Wsk,
    unsigned short* __restrict__ Wt2, int* __restrict__ deg)
{
    const int b = blockIdx.x;
    if (b < 32) {
        int t = b * 256 + threadIdx.x;   // 0..8191
        int m    = t >> 11;
        int ct   = (t >> 8) & 7;
        int ks   = (t >> 6) & 3;
        int lane = t & 63;
        int c  = ct * 16 + (lane & 15);
        int k0 = ks * 32 + (lane >> 4) * 8;
        const float* W = (m == 0) ? Wq : (m == 1) ? Wk : (m == 2) ? Wv : Wsk;
        unsigned short u[8];
        #pragma unroll
        for (int j = 0; j < 8; ++j)
            u[j] = f2bf(W[(size_t)(k0 + j) * FDIM + c]);
        *reinterpret_cast<uint4*>(&Wt2[(size_t)t * 8]) = *reinterpret_cast<uint4*>(u);
    } else {
        int i0 = ((b - 32) * 256 + threadIdx.x) * 4;
        #pragma unroll
        for (int j = 0; j < 4; ++j)
            if (i0 + j < NNODES) deg[i0 + j] = 0;
    }
}

// ---------------------------------------------------------------------------
// MFMA GEMM with in-kernel x conversion (fp32 slab -> LDS bf16) and
// LDS-staged coalesced epilogue. Tail: histogram 1024 edges per block.
// 512 threads (8 waves), 64 rows/block.
// ---------------------------------------------------------------------------
__global__ __launch_bounds__(512) void tgd_gemm_mfma(
    const float* __restrict__ x, const unsigned short* __restrict__ Wt2,
    const float* __restrict__ bq, const float* __restrict__ bk,
    const float* __restrict__ bv, const float* __restrict__ bsk,
    const int* __restrict__ ei, int* __restrict__ deg,
    unsigned short* __restrict__ qb, unsigned short* __restrict__ kv,
    float* __restrict__ outp)
{
    __shared__ float st[64 * 128];                      // 32KB staging
    unsigned short* sth = (unsigned short*)st;

    const int tid  = threadIdx.x;
    const int wave = tid >> 6, lane = tid & 63;
    const int mp   = wave >> 2;           // 0: (q,k)  1: (v,skip)
    const int wr   = wave & 3;
    const int l16  = lane & 15, lhi = lane >> 4;
    const int base = blockIdx.x * 64;

    // ---- stage-in: 64x128 fp32 slab -> LDS bf16 row-major (stride 136) ----
    #pragma unroll
    for (int i = 0; i < 4; ++i) {
        int f = i * 512 + tid;            // float4 slot 0..2047
        int row = f >> 5, c4 = f & 31;
        float4 v4 = {0.f, 0.f, 0.f, 0.f};
        if (base + row < NNODES)
            v4 = *reinterpret_cast<const float4*>(
                &x[(size_t)(base + row) * FDIM + c4 * 4]);
        unsigned short* d = &sth[row * 136 + c4 * 4];
        d[0] = f2bf(v4.x); d[1] = f2bf(v4.y);
        d[2] = f2bf(v4.z); d[3] = f2bf(v4.w);
    }
    __syncthreads();

    // A fragments from LDS: row = wr*16+l16, k = ks*32 + lhi*8 .. +7
    bf16x8 a[4];
    #pragma unroll
    for (int ks = 0; ks < 4; ++ks)
        a[ks] = *reinterpret_cast<const bf16x8*>(
            &sth[(wr * 16 + l16) * 136 + ks * 32 + lhi * 8]);
    __syncthreads();   // all waves done reading stage-in before epilogue reuse

    f32x4 acc[2][8];
    #pragma unroll
    for (int m2 = 0; m2 < 2; ++m2)
        #pragma unroll
        for (int ct = 0; ct < 8; ++ct)
            acc[m2][ct] = (f32x4){0.f, 0.f, 0.f, 0.f};

    #pragma unroll
    for (int ks = 0; ks < 4; ++ks) {
        #pragma unroll
        for (int m2 = 0; m2 < 2; ++m2) {
            const int m = mp * 2 + m2;
            const unsigned short* wb =
                Wt2 + ((size_t)((m * 8 * 4 + ks) * 64) + lane) * 8;
            #pragma unroll
            for (int ct = 0; ct < 8; ++ct) {
                bf16x8 b = *reinterpret_cast<const bf16x8*>(wb + (size_t)ct * 2048);
                acc[m2][ct] = __builtin_amdgcn_mfma_f32_16x16x32_bf16(
                    a[ks], b, acc[m2][ct], 0, 0, 0);
            }
        }
    }

    const int rowl0 = wr * 16 + lhi * 4;

    // ---- phase 1: q -> qb (bf16) ----
    if (mp == 0) {
        #pragma unroll
        for (int ct = 0; ct < 8; ++ct) {
            int col = ct * 16 + l16;
            float bval = bq[col];
            #pragma unroll
            for (int r = 0; r < 4; ++r)
                sth[(rowl0 + r) * 128 + col] = f2bf(acc[0][ct][r] + bval);
        }
    }
    __syncthreads();
    #pragma unroll
    for (int i = 0; i < 2; ++i) {
        int idx = i * 512 + tid;           // uint4 idx in [64][16]
        int row = idx >> 4, c8 = idx & 15;
        if (base + row < NNODES)
            *reinterpret_cast<uint4*>(&qb[(size_t)(base + row) * 128 + c8 * 8]) =
                *reinterpret_cast<const uint4*>(&sth[row * 128 + c8 * 8]);
    }
    __syncthreads();

    // ---- phase 2: skip -> outp (fp32) ----
    if (mp == 1) {
        #pragma unroll
        for (int ct = 0; ct < 8; ++ct) {
            int col = ct * 16 + l16;
            float bval = bsk[col];
            #pragma unroll
            for (int r = 0; r < 4; ++r)
                st[(rowl0 + r) * 128 + col] = acc[1][ct][r] + bval;
        }
    }
    __syncthreads();
    #pragma unroll
    for (int i = 0; i < 4; ++i) {
        int idx = i * 512 + tid;
        int row = idx >> 5, c4 = idx & 31;
        if (base + row < NNODES)
            *reinterpret_cast<float4*>(&outp[(size_t)(base + row) * FDIM + c4 * 4]) =
                *reinterpret_cast<const float4*>(&st[row * 128 + c4 * 4]);
    }
    __syncthreads();

    // ---- phase 3: k | v -> kv bf16 [64][256] ----
    {
        const int off  = (mp == 0) ? 0 : 128;
        const int m2s  = (mp == 0) ? 1 : 0;
        const float* bias = (mp == 0) ? bk : bv;
        #pragma unroll
        for (int ct = 0; ct < 8; ++ct) {
            int col = ct * 16 + l16;
            float bval = bias[col];
            #pragma unroll
            for (int r = 0; r < 4; ++r)
                sth[(rowl0 + r) * 256 + off + col] = f2bf(acc[m2s][ct][r] + bval);
        }
    }
    __syncthreads();
    #pragma unroll
    for (int i = 0; i < 4; ++i) {
        int idx = i * 512 + tid;
        int row = idx >> 5, c8 = idx & 31;
        if (base + row < NNODES)
            *reinterpret_cast<uint4*>(&kv[(size_t)(base + row) * 256 + c8 * 8]) =
                *reinterpret_cast<const uint4*>(&sth[row * 256 + c8 * 8]);
    }

    // ---- hist tail: 1024 edges per block ----
    {
        int e0 = blockIdx.x * 1024 + tid * 2;
        if (e0 < NEDGES)     atomicAdd(&deg[ei[NEDGES + e0]], 1);
        if (e0 + 1 < NEDGES) atomicAdd(&deg[ei[NEDGES + e0 + 1]], 1);
    }
}

// ---------------------------------------------------------------------------
// scan1: local inclusive scan per 1024-block; block total -> bsum
// ---------------------------------------------------------------------------
__global__ __launch_bounds__(1024) void tgd_scan1(const int* __restrict__ deg,
                                                  int* __restrict__ rowptr,
                                                  int* __restrict__ bsum)
{
    __shared__ int buf[1024];
    const int tid = threadIdx.x;
    const int i   = blockIdx.x * 1024 + tid;
    int d = (i < NNODES) ? deg[i] : 0;
    buf[tid] = d;
    __syncthreads();
    #pragma unroll
    for (int off = 1; off < 1024; off <<= 1) {
        int t2 = (tid >= off) ? buf[tid - off] : 0;
        __syncthreads();
        buf[tid] += t2;
        __syncthreads();
    }
    if (i < NNODES) rowptr[i + 1] = buf[tid];
    if (tid == 1023) bsum[blockIdx.x] = buf[1023];
}

// ---------------------------------------------------------------------------
// scan3 (scan2 folded in): each block wave-reduces bsum[0..blockIdx.x-1]
// for its own offset, then applies it and emits write cursors.
// ---------------------------------------------------------------------------
__global__ __launch_bounds__(1024) void tgd_scan3(const int* __restrict__ deg,
                                                  const int* __restrict__ bsum,
                                                  int* __restrict__ rowptr,
                                                  int* __restrict__ ofs)
{
    __shared__ int sboff;
    const int tid = threadIdx.x;
    if (tid < 64) {
        int v = (tid < blockIdx.x) ? bsum[tid] : 0;   // blockIdx.x <= 48
        #pragma unroll
        for (int m = 32; m >= 1; m >>= 1) v += __shfl_xor(v, m);
        if (tid == 0) sboff = v;
    }
    __syncthreads();
    const int i = blockIdx.x * 1024 + tid;
    if (i < NNODES) {
        int r = rowptr[i + 1] + sboff;
        rowptr[i + 1] = r;
        ofs[i] = r - deg[i];
    }
    if (i == 0) rowptr[0] = 0;
}

__global__ __launch_bounds__(256) void tgd_build(const int* __restrict__ ei,
                                                 int* __restrict__ ofs,
                                                 int* __restrict__ csr)
{
    int t = blockIdx.x * 256 + threadIdx.x;
    if (t >= NEDGES) return;
    int src = ei[t];
    int dst = ei[NEDGES + t];
    int pos = atomicAdd(&ofs[dst], 1);
    csr[pos] = src;
}

// ---------------------------------------------------------------------------
// Fused per-dst aggregation: 1 wave per node, unroll-4 (verified 63us r16).
// Lane l loads ushort4 at kv[src*256+4l]: lanes 0..31 k, 32..63 v.
// ---------------------------------------------------------------------------
__global__ __launch_bounds__(256) void tgd_agg(
    const int* __restrict__ csr, const int* __restrict__ rowptr,
    const unsigned short* __restrict__ qb, const unsigned short* __restrict__ kv,
    float* __restrict__ outp)
{
    const int node = blockIdx.x * 4 + (threadIdx.x >> 6);
    const int lane = threadIdx.x & 63;
    if (node >= NNODES) return;
    const int start = rowptr[node];
    const int end   = rowptr[node + 1];
    if (start == end) return;

    const bool isK = (lane < 32);
    float4 qv = {0.f, 0.f, 0.f, 0.f};
    if (isK) {
        ushort4 qu = *reinterpret_cast<const ushort4*>(&qb[(size_t)node * FDIM + lane * 4]);
        qv.x = bf2f(qu.x); qv.y = bf2f(qu.y); qv.z = bf2f(qu.z); qv.w = bf2f(qu.w);
    }
    const float inv = 0.17677669529663687f;  // 1/sqrt(32)

    float  den = 0.0f;
    float4 acc = {0.f, 0.f, 0.f, 0.f};

    for (int base = start; base < end; base += 64) {
        const int cnt = min(64, end - base);
        int myid = (lane < cnt) ? csr[base + lane] : 0;

        int j = 0;
        for (; j + 3 < cnt; j += 4) {
            int s0 = __shfl(myid, j);
            int s1 = __shfl(myid, j + 1);
            int s2 = __shfl(myid, j + 2);
            int s3 = __shfl(myid, j + 3);
            ushort4 r0 = *reinterpret_cast<const ushort4*>(&kv[(size_t)s0 * 256 + lane * 4]);
            ushort4 r1 = *reinterpret_cast<const ushort4*>(&kv[(size_t)s1 * 256 + lane * 4]);
            ushort4 r2 = *reinterpret_cast<const ushort4*>(&kv[(size_t)s2 * 256 + lane * 4]);
            ushort4 r3 = *reinterpret_cast<const ushort4*>(&kv[(size_t)s3 * 256 + lane * 4]);

            float a0 = bf2f(r0.x), a1 = bf2f(r0.y), a2 = bf2f(r0.z), a3 = bf2f(r0.w);
            float b0 = bf2f(r1.x), b1 = bf2f(r1.y), b2 = bf2f(r1.z), b3 = bf2f(r1.w);
            float c0 = bf2f(r2.x), c1 = bf2f(r2.y), c2 = bf2f(r2.z), c3 = bf2f(r2.w);
            float d0 = bf2f(r3.x), d1 = bf2f(r3.y), d2 = bf2f(r3.z), d3 = bf2f(r3.w);

            float sA = qv.x*a0 + qv.y*a1 + qv.z*a2 + qv.w*a3;
            float sB = qv.x*b0 + qv.y*b1 + qv.z*b2 + qv.w*b3;
            float sC = qv.x*c0 + qv.y*c1 + qv.z*c2 + qv.w*c3;
            float sD = qv.x*d0 + qv.y*d1 + qv.z*d2 + qv.w*d3;
            sA += __shfl_xor(sA, 1);  sB += __shfl_xor(sB, 1);
            sC += __shfl_xor(sC, 1);  sD += __shfl_xor(sD, 1);
            sA += __shfl_xor(sA, 2);  sB += __shfl_xor(sB, 2);
            sC += __shfl_xor(sC, 2);  sD += __shfl_xor(sD, 2);
            sA += __shfl_xor(sA, 4);  sB += __shfl_xor(sB, 4);
            sC += __shfl_xor(sC, 4);  sD += __shfl_xor(sD, 4);
            float wA = __expf(sA * inv);
            float wB = __expf(sB * inv);
            float wC = __expf(sC * inv);
            float wD = __expf(sD * inv);
            wA = __shfl_xor(wA, 32);
            wB = __shfl_xor(wB, 32);
            wC = __shfl_xor(wC, 32);
            wD = __shfl_xor(wD, 32);
            if (!isK) {
                den += (wA + wB) + (wC + wD);
                acc.x += wA*a0 + wB*b0 + wC*c0 + wD*d0;
                acc.y += wA*a1 + wB*b1 + wC*c1 + wD*d1;
                acc.z += wA*a2 + wB*b2 + wC*c2 + wD*d2;
                acc.w += wA*a3 + wB*b3 + wC*c3 + wD*d3;
            }
        }
        for (; j + 1 < cnt; j += 2) {
            int s0 = __shfl(myid, j);
            int s1 = __shfl(myid, j + 1);
            ushort4 r0 = *reinterpret_cast<const ushort4*>(&kv[(size_t)s0 * 256 + lane * 4]);
            ushort4 r1 = *reinterpret_cast<const ushort4*>(&kv[(size_t)s1 * 256 + lane * 4]);
            float a0 = bf2f(r0.x), a1 = bf2f(r0.y), a2 = bf2f(r0.z), a3 = bf2f(r0.w);
            float b0 = bf2f(r1.x), b1 = bf2f(r1.y), b2 = bf2f(r1.z), b3 = bf2f(r1.w);
            float sA = qv.x*a0 + qv.y*a1 + qv.z*a2 + qv.w*a3;
            float sB = qv.x*b0 + qv.y*b1 + qv.z*b2 + qv.w*b3;
            sA += __shfl_xor(sA, 1);  sB += __shfl_xor(sB, 1);
            sA += __shfl_xor(sA, 2);  sB += __shfl_xor(sB, 2);
            sA += __shfl_xor(sA, 4);  sB += __shfl_xor(sB, 4);
            float wA = __expf(sA * inv);
            float wB = __expf(sB * inv);
            wA = __shfl_xor(wA, 32);
            wB = __shfl_xor(wB, 32);
            if (!isK) {
                den += wA + wB;
                acc.x += wA*a0 + wB*b0;
                acc.y += wA*a1 + wB*b1;
                acc.z += wA*a2 + wB*b2;
                acc.w += wA*a3 + wB*b3;
            }
        }
        if (j < cnt) {
            int s0 = __shfl(myid, j);
            ushort4 r0 = *reinterpret_cast<const ushort4*>(&kv[(size_t)s0 * 256 + lane * 4]);
            float a0 = bf2f(r0.x), a1 = bf2f(r0.y), a2 = bf2f(r0.z), a3 = bf2f(r0.w);
            float sA = qv.x*a0 + qv.y*a1 + qv.z*a2 + qv.w*a3;
            sA += __shfl_xor(sA, 1);
            sA += __shfl_xor(sA, 2);
            sA += __shfl_xor(sA, 4);
            float wA = __expf(sA * inv);
            wA = __shfl_xor(wA, 32);
            if (!isK) {
                den += wA;
                acc.x += wA*a0; acc.y += wA*a1; acc.z += wA*a2; acc.w += wA*a3;
            }
        }
    }

    if (!isK) {
        float invd = 1.0f / den;
        float4* o = reinterpret_cast<float4*>(&outp[(size_t)node * FDIM + (lane - 32) * 4]);
        float4 cur = *o;
        cur.x += acc.x * invd;
        cur.y += acc.y * invd;
        cur.z += acc.z * invd;
        cur.w += acc.w * invd;
        *o = cur;
    }
}

// ---------------------------------------------------------------------------
extern "C" void kernel_launch(void* const* d_in, const int* in_sizes, int n_in,
                              void* d_out, int out_size, void* d_ws, size_t ws_size,
                              hipStream_t stream) {
    const float* x   = (const float*)d_in[0];
    const int*   ei  = (const int*)  d_in[1];
    const float* Wq  = (const float*)d_in[2];
    const float* bq  = (const float*)d_in[3];
    const float* Wk  = (const float*)d_in[4];
    const float* bk  = (const float*)d_in[5];
    const float* Wv  = (const float*)d_in[6];
    const float* bv  = (const float*)d_in[7];
    const float* Wsk = (const float*)d_in[8];
    const float* bsk = (const float*)d_in[9];
    float* outp = (float*)d_out;

    unsigned short* qb  = (unsigned short*)d_ws;                    // N*128 bf16 (12.8MB)
    unsigned short* kv  = qb + (size_t)NNODES * FDIM;               // N*256 bf16 (25.6MB)
    unsigned short* Wt2 = kv + (size_t)NNODES * 256;                // 128KB
    int* deg    = (int*)(Wt2 + 4 * FDIM * FDIM);
    int* rowptr = deg + NNODES;            // N+1
    int* ofs    = rowptr + NNODES + 1;     // N
    int* csr    = ofs + NNODES;            // E
    int* bsum   = csr + NEDGES;            // 49

    // 1: weights -> fragment order; zero deg
    tgd_prep<<<32 + NSCANB, 256, 0, stream>>>(Wq, Wk, Wv, Wsk, Wt2, deg);

    // 2: GEMM (in-kernel x conversion) + edge histogram tail
    tgd_gemm_mfma<<<NBLK, 512, 0, stream>>>(
        x, Wt2, bq, bk, bv, bsk, ei, deg, qb, kv, outp);

    // 3-5: CSR build
    tgd_scan1<<<NSCANB, 1024, 0, stream>>>(deg, rowptr, bsum);
    tgd_scan3<<<NSCANB, 1024, 0, stream>>>(deg, bsum, rowptr, ofs);
    tgd_build<<<(NEDGES + 255) / 256, 256, 0, stream>>>(ei, ofs, csr);

    // 6: fused attention aggregation
    tgd_agg<<<(NNODES + 3) / 4, 256, 0, stream>>>(csr, rowptr, qb, kv, outp);
}